// Round 1
// baseline (131.159 us; speedup 1.0000x reference)
//
#include <hip/hip_runtime.h>

#define B_SZ  4
#define N_TOK 4096   // H*W
#define CH    256
#define CR    32
#define SEG   512    // keys per wave (split-K segment), 8 waves/block
#define KT    64     // keys per iteration
#define NITER (SEG / KT)
#define LOG2E 1.44269504f

typedef __attribute__((ext_vector_type(8))) short bf16x8;  // 8 bf16 = 4 VGPRs
typedef __attribute__((ext_vector_type(4))) float f32x4;

__device__ inline ushort f2bf(float x) {           // RNE fp32->bf16
    uint u = __float_as_uint(x);
    u += 0x7fff + ((u >> 16) & 1);
    return (ushort)(u >> 16);
}
__device__ inline uint pk2bf(float a, float b) {   // [bf16(b)|bf16(a)], truncate
    return __builtin_amdgcn_perm(__float_as_uint(b), __float_as_uint(a), 0x07060302);
}
__device__ inline float fast_exp2(float x) {       // raw v_exp_f32 (1 instr) when available
#if __has_builtin(__builtin_amdgcn_exp2f)
    return __builtin_amdgcn_exp2f(x);
#else
    return exp2f(x);
#endif
}

// exp2 a score fragment, pack to bf16, store 8B to LDS (no shift: constant factor
// cancels in p/sum(p); |s*log2e| <= ~49 so p,sums stay well inside fp32 range)
__device__ inline void exp_pack_store(const f32x4 v, ushort* dst) {
    float p0 = fast_exp2(v[0]), p1 = fast_exp2(v[1]);
    float p2 = fast_exp2(v[2]), p3 = fast_exp2(v[3]);
    uint2 w; w.x = pk2bf(p0, p1); w.y = pk2bf(p2, p3);
    *(uint2*)dst = w;
}

// ---------- Kernel 0: weight prep — Wf/Wg/Wh -> transposed bf16 [32][256]; Wv -> [256][32] bf16 ----------
__global__ __launch_bounds__(256) void prep_kernel(
    const float* __restrict__ Wf, const float* __restrict__ Wg,
    const float* __restrict__ Wh, const float* __restrict__ Wv,
    ushort* __restrict__ wft, ushort* __restrict__ wgt,
    ushort* __restrict__ wht, ushort* __restrict__ wvt)
{
    int t = threadIdx.x, blk = blockIdx.x;
    if (blk < 3) {
        const float* W  = (blk == 0) ? Wf : (blk == 1) ? Wg : Wh;
        ushort*      Wt = (blk == 0) ? wft : (blk == 1) ? wgt : wht;
        int j = t & 31, half = t >> 5;
        ushort tmp[32];
        #pragma unroll
        for (int kk = 0; kk < 32; ++kk)
            tmp[kk] = f2bf(W[(half * 32 + kk) * CR + j]);
        ushort* dst = Wt + (size_t)j * CH + half * 32;
        #pragma unroll
        for (int k8 = 0; k8 < 4; ++k8)
            *(bf16x8*)(dst + k8 * 8) = *(bf16x8*)&tmp[k8 * 8];
    } else {
        ushort tmp[32];
        #pragma unroll
        for (int k = 0; k < CR; ++k) tmp[k] = f2bf(Wv[k * CH + t]);
        ushort* dst = wvt + (size_t)t * CR;
        #pragma unroll
        for (int k8 = 0; k8 < 4; ++k8)
            *(bf16x8*)(dst + k8 * 8) = *(bf16x8*)&tmp[k8 * 8];
    }
}

// ---------- Kernel A: MFMA projections, 4-way split-K. g is scaled by log2(e). ----------
__global__ __launch_bounds__(256) void proj_kernel(
    const float* __restrict__ x,
    const ushort* __restrict__ wft, const ushort* __restrict__ wgt, const ushort* __restrict__ wht,
    const float* __restrict__ bf_, const float* __restrict__ bg, const float* __restrict__ bh,
    ushort* __restrict__ fo, ushort* __restrict__ go, ushort* __restrict__ hto)
{
    __shared__ f32x4 accx[3][6][64];   // partial accs from waves 1..3 (18 KB)
    int t  = threadIdx.x;
    int wv = t >> 6, L = t & 63, nl = L & 15, Q = L >> 4;
    int row_t = blockIdx.x * 16;
    int b = row_t >> 12, tok0 = row_t & 4095;

    const float* xrow = x + (size_t)(row_t + nl) * CH;
    f32x4 A[6];
    #pragma unroll
    for (int i = 0; i < 6; ++i) A[i] = (f32x4){0.f, 0.f, 0.f, 0.f};

    #pragma unroll
    for (int c2 = 0; c2 < 2; ++c2) {
        int off = wv * 64 + c2 * 32 + Q * 8;
        float4 lo = *(const float4*)(xrow + off);
        float4 hi = *(const float4*)(xrow + off + 4);
        bf16x8 xa;
        xa[0] = (short)f2bf(lo.x); xa[1] = (short)f2bf(lo.y);
        xa[2] = (short)f2bf(lo.z); xa[3] = (short)f2bf(lo.w);
        xa[4] = (short)f2bf(hi.x); xa[5] = (short)f2bf(hi.y);
        xa[6] = (short)f2bf(hi.z); xa[7] = (short)f2bf(hi.w);

        bf16x8 wf0 = *(const bf16x8*)(wft + (size_t)nl * CH + off);
        bf16x8 wf1 = *(const bf16x8*)(wft + (size_t)(16 + nl) * CH + off);
        bf16x8 wg0 = *(const bf16x8*)(wgt + (size_t)nl * CH + off);
        bf16x8 wg1 = *(const bf16x8*)(wgt + (size_t)(16 + nl) * CH + off);
        bf16x8 wh0 = *(const bf16x8*)(wht + (size_t)nl * CH + off);
        bf16x8 wh1 = *(const bf16x8*)(wht + (size_t)(16 + nl) * CH + off);

        A[0] = __builtin_amdgcn_mfma_f32_16x16x32_bf16(xa, wf0, A[0], 0, 0, 0);
        A[1] = __builtin_amdgcn_mfma_f32_16x16x32_bf16(xa, wf1, A[1], 0, 0, 0);
        A[2] = __builtin_amdgcn_mfma_f32_16x16x32_bf16(xa, wg0, A[2], 0, 0, 0);
        A[3] = __builtin_amdgcn_mfma_f32_16x16x32_bf16(xa, wg1, A[3], 0, 0, 0);
        A[4] = __builtin_amdgcn_mfma_f32_16x16x32_bf16(wh0, xa, A[4], 0, 0, 0);  // h^T
        A[5] = __builtin_amdgcn_mfma_f32_16x16x32_bf16(wh1, xa, A[5], 0, 0, 0);
    }

    if (wv > 0) {
        #pragma unroll
        for (int i = 0; i < 6; ++i) accx[wv - 1][i][L] = A[i];
    }
    __syncthreads();
    if (wv == 0) {
        #pragma unroll
        for (int i = 0; i < 6; ++i) {
            f32x4 s0 = accx[0][i][L], s1 = accx[1][i][L], s2 = accx[2][i][L];
            A[i] = A[i] + s0 + s1 + s2;
        }
        float bF0 = bf_[nl], bF1 = bf_[16 + nl];
        float bG0 = bg[nl] * LOG2E, bG1 = bg[16 + nl] * LOG2E;
        #pragma unroll
        for (int r = 0; r < 4; ++r) {
            size_t ro = (size_t)(row_t + Q * 4 + r) * CR;
            fo[ro + nl]      = f2bf(A[0][r] + bF0);
            fo[ro + 16 + nl] = f2bf(A[1][r] + bF1);
            go[ro + nl]      = f2bf(fmaf(A[2][r], LOG2E, bG0));
            go[ro + 16 + nl] = f2bf(fmaf(A[3][r], LOG2E, bG1));
        }
        ushort* hb = hto + (size_t)b * CR * N_TOK + tok0 + nl;
        #pragma unroll
        for (int r = 0; r < 4; ++r) {
            int ch = Q * 4 + r;
            hb[(size_t)ch * N_TOK]        = f2bf(A[4][r] + bh[ch]);
            hb[(size_t)(16 + ch) * N_TOK] = f2bf(A[5][r] + bh[16 + ch]);
        }
    }
}

// ---------- Kernel B: attention — 8 waves x 512-key split-K, 32 queries/block ----------
// R7: software-pipelined (P-read/b-load issue -> QK(it+1)+exp+P-write -> PV(it)),
//     XCD-swizzled blockIdx (each XCD's L2 holds one batch's f/ht),
//     no softmax shift, rowsum via MFMA ones-fragment, setprio around PV cluster.
__global__ __launch_bounds__(512, 4) void attn_kernel(
    const ushort* __restrict__ f, const ushort* __restrict__ g,
    const ushort* __restrict__ ht, const ushort* __restrict__ wvt,
    const float* __restrict__ bv, const float* __restrict__ gamma,
    const float* __restrict__ x, float* __restrict__ out)
{
    // 38912 B shared, aliased: K-loop = pls[8][32][76] ushort;
    // post-barrier = obuf[8][32][33] f32 (33792) + lbuf[8][32] (1024) + oc[32][48] ushort (3072)
    __shared__ unsigned long long smem_raw[38912 / 8];
    ushort (*pls)[32][76]  = (ushort (*)[32][76])smem_raw;
    float  (*obuf)[32][33] = (float (*)[32][33])smem_raw;
    float  (*lbuf)[32]     = (float (*)[32])((char*)smem_raw + 33792);
    ushort (*oc)[48]       = (ushort (*)[48])((char*)smem_raw + 34816);

    int t  = threadIdx.x;
    int wv = t >> 6;
    int L  = t & 63;
    int nl = L & 15;
    int Q  = L >> 4;
    // XCD-aware bijective swizzle: 512 blocks = 8 XCDs x 64. Consecutive blockIdx
    // round-robin over XCDs; remap so each XCD gets 64 consecutive work items
    // (= half of one batch) -> per-XCD f/ht working set is 1 MB, L2-resident.
    int bid = blockIdx.x;
    int swz = (bid & 7) * 64 + (bid >> 3);
    int b  = swz >> 7;
    int q0 = (swz & 127) * 32;

    const ushort* fb  = f  + (size_t)b * N_TOK * CR;
    const ushort* htb = ht + (size_t)b * CR * N_TOK;

    bf16x8 gB0 = *(const bf16x8*)(g + ((size_t)b * N_TOK + q0 + nl) * CR + Q * 8);
    bf16x8 gB1 = *(const bf16x8*)(g + ((size_t)b * N_TOK + q0 + 16 + nl) * CR + Q * 8);

    f32x4 acc00 = {0,0,0,0}, acc01 = {0,0,0,0};   // [qh][chhalf]
    f32x4 acc10 = {0,0,0,0}, acc11 = {0,0,0,0};
    f32x4 accS0 = {0,0,0,0}, accS1 = {0,0,0,0};   // rowsum accumulators (ones-frag MFMA)
    const f32x4 zf = {0,0,0,0};

    bf16x8 ones;
    #pragma unroll
    for (int i = 0; i < 8; ++i) ones[i] = (short)0x3F80;   // bf16 1.0

    int key0 = wv * SEG;

    // ---- prologue: A(0), A(1) loads; QK(0); exp/pack -> P(0) ----
    bf16x8 Ap0 = *(const bf16x8*)(fb + (size_t)(key0 +  0 + nl) * CR + Q * 8);
    bf16x8 Ap1 = *(const bf16x8*)(fb + (size_t)(key0 + 16 + nl) * CR + Q * 8);
    bf16x8 Ap2 = *(const bf16x8*)(fb + (size_t)(key0 + 32 + nl) * CR + Q * 8);
    bf16x8 Ap3 = *(const bf16x8*)(fb + (size_t)(key0 + 48 + nl) * CR + Q * 8);
    bf16x8 An0 = *(const bf16x8*)(fb + (size_t)(key0 + KT +  0 + nl) * CR + Q * 8);
    bf16x8 An1 = *(const bf16x8*)(fb + (size_t)(key0 + KT + 16 + nl) * CR + Q * 8);
    bf16x8 An2 = *(const bf16x8*)(fb + (size_t)(key0 + KT + 32 + nl) * CR + Q * 8);
    bf16x8 An3 = *(const bf16x8*)(fb + (size_t)(key0 + KT + 48 + nl) * CR + Q * 8);

    {
        f32x4 s0 = __builtin_amdgcn_mfma_f32_16x16x32_bf16(Ap0, gB0, zf, 0, 0, 0);
        f32x4 s1 = __builtin_amdgcn_mfma_f32_16x16x32_bf16(Ap1, gB0, zf, 0, 0, 0);
        f32x4 s2 = __builtin_amdgcn_mfma_f32_16x16x32_bf16(Ap2, gB0, zf, 0, 0, 0);
        f32x4 s3 = __builtin_amdgcn_mfma_f32_16x16x32_bf16(Ap3, gB0, zf, 0, 0, 0);
        exp_pack_store(s0, &pls[wv][nl][ 0 + Q * 4]);
        exp_pack_store(s1, &pls[wv][nl][16 + Q * 4]);
        exp_pack_store(s2, &pls[wv][nl][32 + Q * 4]);
        exp_pack_store(s3, &pls[wv][nl][48 + Q * 4]);
        s0 = __builtin_amdgcn_mfma_f32_16x16x32_bf16(Ap0, gB1, zf, 0, 0, 0);
        s1 = __builtin_amdgcn_mfma_f32_16x16x32_bf16(Ap1, gB1, zf, 0, 0, 0);
        s2 = __builtin_amdgcn_mfma_f32_16x16x32_bf16(Ap2, gB1, zf, 0, 0, 0);
        s3 = __builtin_amdgcn_mfma_f32_16x16x32_bf16(Ap3, gB1, zf, 0, 0, 0);
        exp_pack_store(s0, &pls[wv][16 + nl][ 0 + Q * 4]);
        exp_pack_store(s1, &pls[wv][16 + nl][16 + Q * 4]);
        exp_pack_store(s2, &pls[wv][16 + nl][32 + Q * 4]);
        exp_pack_store(s3, &pls[wv][16 + nl][48 + Q * 4]);
    }

    // ---- main loop: per it — issue P(it) reads + b(it) loads; QK(it+1)+exp+write P(it+1); PV(it) ----
    #pragma unroll
    for (int it = 0; it < NITER; ++it) {
        // (1) issue P(it) A-frag reads (wave-private, in-order DS: safe vs later writes)
        bf16x8 aP00 = *(const bf16x8*)&pls[wv][     nl][ 0 + Q * 8];
        bf16x8 aP01 = *(const bf16x8*)&pls[wv][     nl][32 + Q * 8];
        bf16x8 aP10 = *(const bf16x8*)&pls[wv][16 + nl][ 0 + Q * 8];
        bf16x8 aP11 = *(const bf16x8*)&pls[wv][16 + nl][32 + Q * 8];
        // (2) issue ht B-frag loads for it
        int kc = key0 + it * KT;
        const ushort* hk = htb + (size_t)nl * N_TOK + kc;
        bf16x8 b00 = *(const bf16x8*)(hk + Q * 8);
        bf16x8 b01 = *(const bf16x8*)(hk + (size_t)16 * N_TOK + Q * 8);
        bf16x8 b10 = *(const bf16x8*)(hk + 32 + Q * 8);
        bf16x8 b11 = *(const bf16x8*)(hk + (size_t)16 * N_TOK + 32 + Q * 8);

        if (it + 1 < NITER) {
            // (3a) prefetch A(it+2) (clamped reload of A(0) on the tail — never consumed)
            int kn = key0 + ((it + 2 < NITER) ? it + 2 : 0) * KT;
            const ushort* fn = fb + (size_t)kn * CR;
            bf16x8 Nx0 = *(const bf16x8*)(fn + (size_t)( 0 + nl) * CR + Q * 8);
            bf16x8 Nx1 = *(const bf16x8*)(fn + (size_t)(16 + nl) * CR + Q * 8);
            bf16x8 Nx2 = *(const bf16x8*)(fn + (size_t)(32 + nl) * CR + Q * 8);
            bf16x8 Nx3 = *(const bf16x8*)(fn + (size_t)(48 + nl) * CR + Q * 8);
            // (3b) QK(it+1) half 0 + exp/pack/write — covers the P-read and b-load latencies
            f32x4 s0 = __builtin_amdgcn_mfma_f32_16x16x32_bf16(An0, gB0, zf, 0, 0, 0);
            f32x4 s1 = __builtin_amdgcn_mfma_f32_16x16x32_bf16(An1, gB0, zf, 0, 0, 0);
            f32x4 s2 = __builtin_amdgcn_mfma_f32_16x16x32_bf16(An2, gB0, zf, 0, 0, 0);
            f32x4 s3 = __builtin_amdgcn_mfma_f32_16x16x32_bf16(An3, gB0, zf, 0, 0, 0);
            exp_pack_store(s0, &pls[wv][nl][ 0 + Q * 4]);
            exp_pack_store(s1, &pls[wv][nl][16 + Q * 4]);
            exp_pack_store(s2, &pls[wv][nl][32 + Q * 4]);
            exp_pack_store(s3, &pls[wv][nl][48 + Q * 4]);
            // QK(it+1) half 1
            s0 = __builtin_amdgcn_mfma_f32_16x16x32_bf16(An0, gB1, zf, 0, 0, 0);
            s1 = __builtin_amdgcn_mfma_f32_16x16x32_bf16(An1, gB1, zf, 0, 0, 0);
            s2 = __builtin_amdgcn_mfma_f32_16x16x32_bf16(An2, gB1, zf, 0, 0, 0);
            s3 = __builtin_amdgcn_mfma_f32_16x16x32_bf16(An3, gB1, zf, 0, 0, 0);
            exp_pack_store(s0, &pls[wv][16 + nl][ 0 + Q * 4]);
            exp_pack_store(s1, &pls[wv][16 + nl][16 + Q * 4]);
            exp_pack_store(s2, &pls[wv][16 + nl][32 + Q * 4]);
            exp_pack_store(s3, &pls[wv][16 + nl][48 + Q * 4]);
            An0 = Nx0; An1 = Nx1; An2 = Nx2; An3 = Nx3;
        }

        // (4) PV(it) + rowsum MFMAs (pure-MFMA cluster)
        __builtin_amdgcn_s_setprio(1);
        acc00 = __builtin_amdgcn_mfma_f32_16x16x32_bf16(aP00, b00, acc00, 0, 0, 0);
        acc01 = __builtin_amdgcn_mfma_f32_16x16x32_bf16(aP00, b01, acc01, 0, 0, 0);
        acc10 = __builtin_amdgcn_mfma_f32_16x16x32_bf16(aP10, b00, acc10, 0, 0, 0);
        acc11 = __builtin_amdgcn_mfma_f32_16x16x32_bf16(aP10, b01, acc11, 0, 0, 0);
        acc00 = __builtin_amdgcn_mfma_f32_16x16x32_bf16(aP01, b10, acc00, 0, 0, 0);
        acc01 = __builtin_amdgcn_mfma_f32_16x16x32_bf16(aP01, b11, acc01, 0, 0, 0);
        acc10 = __builtin_amdgcn_mfma_f32_16x16x32_bf16(aP11, b10, acc10, 0, 0, 0);
        acc11 = __builtin_amdgcn_mfma_f32_16x16x32_bf16(aP11, b11, acc11, 0, 0, 0);
        accS0 = __builtin_amdgcn_mfma_f32_16x16x32_bf16(aP00, ones, accS0, 0, 0, 0);
        accS0 = __builtin_amdgcn_mfma_f32_16x16x32_bf16(aP01, ones, accS0, 0, 0, 0);
        accS1 = __builtin_amdgcn_mfma_f32_16x16x32_bf16(aP10, ones, accS1, 0, 0, 0);
        accS1 = __builtin_amdgcn_mfma_f32_16x16x32_bf16(aP11, ones, accS1, 0, 0, 0);
        __builtin_amdgcn_s_setprio(0);
    }

    __syncthreads();   // all pls reads done before aliasing as obuf
    #pragma unroll
    for (int r = 0; r < 4; ++r) {
        obuf[wv][     Q * 4 + r][nl]      = acc00[r];
        obuf[wv][     Q * 4 + r][16 + nl] = acc01[r];
        obuf[wv][16 + Q * 4 + r][nl]      = acc10[r];
        obuf[wv][16 + Q * 4 + r][16 + nl] = acc11[r];
    }
    if (nl == 0) {   // lanes 0,16,32,48: accS cols are all identical; row = query
        #pragma unroll
        for (int r = 0; r < 4; ++r) {
            lbuf[wv][     Q * 4 + r] = accS0[r];
            lbuf[wv][16 + Q * 4 + r] = accS1[r];
        }
    }
    __syncthreads();

    {
        int ch = t & 31, qb = t >> 5;   // 512 thr -> 2 (q,ch) each
        #pragma unroll
        for (int qq = qb; qq < 32; qq += 16) {
            float s = 0.f, Lq = 0.f;
            #pragma unroll
            for (int w = 0; w < 8; ++w) { s += obuf[w][qq][ch]; Lq += lbuf[w][qq]; }
            oc[qq][ch] = f2bf(s / Lq);
        }
    }
    __syncthreads();

    // fused epilogue: out = gamma*(o@Wv + bv) + x ; wave wv covers out-ch [wv*32, wv*32+32)
    bf16x8 aO0 = *(const bf16x8*)&oc[     nl][Q * 8];
    bf16x8 aO1 = *(const bf16x8*)&oc[16 + nl][Q * 8];
    float gm = gamma[0];
    const float* xb = x   + ((size_t)b * N_TOK + q0) * CH;
    float*       ob = out + ((size_t)b * N_TOK + q0) * CH;
    #pragma unroll
    for (int i = 0; i < 2; ++i) {
        int nb = wv * 2 + i;
        bf16x8 bW = *(const bf16x8*)(wvt + (size_t)(nb * 16 + nl) * CR + Q * 8);
        f32x4 d0 = __builtin_amdgcn_mfma_f32_16x16x32_bf16(aO0, bW, zf, 0, 0, 0);
        f32x4 d1 = __builtin_amdgcn_mfma_f32_16x16x32_bf16(aO1, bW, zf, 0, 0, 0);
        int c = nb * 16 + nl;
        float bvc = bv[c];
        #pragma unroll
        for (int r = 0; r < 4; ++r) {
            int qa = Q * 4 + r;
            ob[qa * CH + c]        = fmaf(gm, d0[r] + bvc, xb[qa * CH + c]);
            ob[(16 + qa) * CH + c] = fmaf(gm, d1[r] + bvc, xb[(16 + qa) * CH + c]);
        }
    }
}

extern "C" void kernel_launch(void* const* d_in, const int* in_sizes, int n_in,
                              void* d_out, int out_size, void* d_ws, size_t ws_size,
                              hipStream_t stream) {
    const float* x     = (const float*)d_in[0];
    const float* Wf    = (const float*)d_in[1];
    const float* bf_   = (const float*)d_in[2];
    const float* Wg    = (const float*)d_in[3];
    const float* bg    = (const float*)d_in[4];
    const float* Wh    = (const float*)d_in[5];
    const float* bh    = (const float*)d_in[6];
    const float* Wv    = (const float*)d_in[7];
    const float* bv    = (const float*)d_in[8];
    const float* gamma = (const float*)d_in[9];
    float* out = (float*)d_out;

    const size_t T = (size_t)B_SZ * N_TOK * CR;     // 524288
    ushort* fo  = (ushort*)d_ws;
    ushort* go  = fo + T;
    ushort* hto = go + T;
    ushort* wvt = hto + T;                          // 256*32
    ushort* wft = wvt + CH * CR;                    // 32*256 each
    ushort* wgt = wft + CH * CR;
    ushort* wht = wgt + CH * CR;

    prep_kernel<<<4, 256, 0, stream>>>(Wf, Wg, Wh, Wv, wft, wgt, wht, wvt);
    proj_kernel<<<B_SZ * N_TOK / 16, 256, 0, stream>>>(x, wft, wgt, wht, bf_, bg, bh, fo, go, hto);
    attn_kernel<<<B_SZ * (N_TOK / 32), 512, 0, stream>>>(fo, go, hto, wvt, bv, gamma, x, out);
}

// Round 2
// 125.553 us; speedup vs baseline: 1.0447x; 1.0447x over previous
//
#include <hip/hip_runtime.h>

#define B_SZ  4
#define N_TOK 4096   // H*W
#define CH    256
#define CR    32
#define SEG   512    // keys per wave (split-K segment), 8 waves/block
#define KT    64     // keys per iteration
#define NITER (SEG / KT)
#define LOG2E 1.44269504f

typedef __attribute__((ext_vector_type(8))) short bf16x8;  // 8 bf16 = 4 VGPRs
typedef __attribute__((ext_vector_type(4))) float f32x4;

__device__ inline ushort f2bf(float x) {           // RNE fp32->bf16
    uint u = __float_as_uint(x);
    u += 0x7fff + ((u >> 16) & 1);
    return (ushort)(u >> 16);
}
__device__ inline uint pk2bf(float a, float b) {   // [bf16(b)|bf16(a)], truncate
    return __builtin_amdgcn_perm(__float_as_uint(b), __float_as_uint(a), 0x07060302);
}
__device__ inline float fast_exp2(float x) {       // raw v_exp_f32 (1 instr) when available
#if __has_builtin(__builtin_amdgcn_exp2f)
    return __builtin_amdgcn_exp2f(x);
#else
    return exp2f(x);
#endif
}

// ---------- Kernel 0: weight prep — Wf/Wg/Wh -> transposed bf16 [32][256]; Wv -> [256][32] bf16 ----------
__global__ __launch_bounds__(256) void prep_kernel(
    const float* __restrict__ Wf, const float* __restrict__ Wg,
    const float* __restrict__ Wh, const float* __restrict__ Wv,
    ushort* __restrict__ wft, ushort* __restrict__ wgt,
    ushort* __restrict__ wht, ushort* __restrict__ wvt)
{
    int t = threadIdx.x, blk = blockIdx.x;
    if (blk < 3) {
        const float* W  = (blk == 0) ? Wf : (blk == 1) ? Wg : Wh;
        ushort*      Wt = (blk == 0) ? wft : (blk == 1) ? wgt : wht;
        int j = t & 31, half = t >> 5;
        ushort tmp[32];
        #pragma unroll
        for (int kk = 0; kk < 32; ++kk)
            tmp[kk] = f2bf(W[(half * 32 + kk) * CR + j]);
        ushort* dst = Wt + (size_t)j * CH + half * 32;
        #pragma unroll
        for (int k8 = 0; k8 < 4; ++k8)
            *(bf16x8*)(dst + k8 * 8) = *(bf16x8*)&tmp[k8 * 8];
    } else {
        ushort tmp[32];
        #pragma unroll
        for (int k = 0; k < CR; ++k) tmp[k] = f2bf(Wv[k * CH + t]);
        ushort* dst = wvt + (size_t)t * CR;
        #pragma unroll
        for (int k8 = 0; k8 < 4; ++k8)
            *(bf16x8*)(dst + k8 * 8) = *(bf16x8*)&tmp[k8 * 8];
    }
}

// ---------- Kernel A: MFMA projections, 4-way split-K. g is scaled by log2(e). ----------
__global__ __launch_bounds__(256) void proj_kernel(
    const float* __restrict__ x,
    const ushort* __restrict__ wft, const ushort* __restrict__ wgt, const ushort* __restrict__ wht,
    const float* __restrict__ bf_, const float* __restrict__ bg, const float* __restrict__ bh,
    ushort* __restrict__ fo, ushort* __restrict__ go, ushort* __restrict__ hto)
{
    __shared__ f32x4 accx[3][6][64];   // partial accs from waves 1..3 (18 KB)
    int t  = threadIdx.x;
    int wv = t >> 6, L = t & 63, nl = L & 15, Q = L >> 4;
    int row_t = blockIdx.x * 16;
    int b = row_t >> 12, tok0 = row_t & 4095;

    const float* xrow = x + (size_t)(row_t + nl) * CH;
    f32x4 A[6];
    #pragma unroll
    for (int i = 0; i < 6; ++i) A[i] = (f32x4){0.f, 0.f, 0.f, 0.f};

    #pragma unroll
    for (int c2 = 0; c2 < 2; ++c2) {
        int off = wv * 64 + c2 * 32 + Q * 8;
        float4 lo = *(const float4*)(xrow + off);
        float4 hi = *(const float4*)(xrow + off + 4);
        bf16x8 xa;
        xa[0] = (short)f2bf(lo.x); xa[1] = (short)f2bf(lo.y);
        xa[2] = (short)f2bf(lo.z); xa[3] = (short)f2bf(lo.w);
        xa[4] = (short)f2bf(hi.x); xa[5] = (short)f2bf(hi.y);
        xa[6] = (short)f2bf(hi.z); xa[7] = (short)f2bf(hi.w);

        bf16x8 wf0 = *(const bf16x8*)(wft + (size_t)nl * CH + off);
        bf16x8 wf1 = *(const bf16x8*)(wft + (size_t)(16 + nl) * CH + off);
        bf16x8 wg0 = *(const bf16x8*)(wgt + (size_t)nl * CH + off);
        bf16x8 wg1 = *(const bf16x8*)(wgt + (size_t)(16 + nl) * CH + off);
        bf16x8 wh0 = *(const bf16x8*)(wht + (size_t)nl * CH + off);
        bf16x8 wh1 = *(const bf16x8*)(wht + (size_t)(16 + nl) * CH + off);

        A[0] = __builtin_amdgcn_mfma_f32_16x16x32_bf16(xa, wf0, A[0], 0, 0, 0);
        A[1] = __builtin_amdgcn_mfma_f32_16x16x32_bf16(xa, wf1, A[1], 0, 0, 0);
        A[2] = __builtin_amdgcn_mfma_f32_16x16x32_bf16(xa, wg0, A[2], 0, 0, 0);
        A[3] = __builtin_amdgcn_mfma_f32_16x16x32_bf16(xa, wg1, A[3], 0, 0, 0);
        A[4] = __builtin_amdgcn_mfma_f32_16x16x32_bf16(wh0, xa, A[4], 0, 0, 0);  // h^T
        A[5] = __builtin_amdgcn_mfma_f32_16x16x32_bf16(wh1, xa, A[5], 0, 0, 0);
    }

    if (wv > 0) {
        #pragma unroll
        for (int i = 0; i < 6; ++i) accx[wv - 1][i][L] = A[i];
    }
    __syncthreads();
    if (wv == 0) {
        #pragma unroll
        for (int i = 0; i < 6; ++i) {
            f32x4 s0 = accx[0][i][L], s1 = accx[1][i][L], s2 = accx[2][i][L];
            A[i] = A[i] + s0 + s1 + s2;
        }
        float bF0 = bf_[nl], bF1 = bf_[16 + nl];
        float bG0 = bg[nl] * LOG2E, bG1 = bg[16 + nl] * LOG2E;
        #pragma unroll
        for (int r = 0; r < 4; ++r) {
            size_t ro = (size_t)(row_t + Q * 4 + r) * CR;
            fo[ro + nl]      = f2bf(A[0][r] + bF0);
            fo[ro + 16 + nl] = f2bf(A[1][r] + bF1);
            go[ro + nl]      = f2bf(fmaf(A[2][r], LOG2E, bG0));
            go[ro + 16 + nl] = f2bf(fmaf(A[3][r], LOG2E, bG1));
        }
        ushort* hb = hto + (size_t)b * CR * N_TOK + tok0 + nl;
        #pragma unroll
        for (int r = 0; r < 4; ++r) {
            int ch = Q * 4 + r;
            hb[(size_t)ch * N_TOK]        = f2bf(A[4][r] + bh[ch]);
            hb[(size_t)(16 + ch) * N_TOK] = f2bf(A[5][r] + bh[16 + ch]);
        }
    }
}

// ---------- Kernel B: attention — 8 waves x 512-key split-K, 32 queries/block, pipelined (R6 structure) ----------
// R8 = R6 + (a) XCD-bijective block swizzle (per-XCD L2 working set = 1 batch's f/ht)
//         + (b) softmax shift removed (exp2(s)/sum invariant; p<=2^49, sums<=2^58, fp32-safe)
__global__ __launch_bounds__(512, 4) void attn_kernel(
    const ushort* __restrict__ f, const ushort* __restrict__ g,
    const ushort* __restrict__ ht, const ushort* __restrict__ wvt,
    const float* __restrict__ bv, const float* __restrict__ gamma,
    const float* __restrict__ x, float* __restrict__ out)
{
    // 38912 B shared, aliased: K-loop = pls[8][32][76] ushort;
    // post-barrier = obuf[8][32][33] f32 (33792) + lbuf[8][32] (1024) + oc[32][48] ushort (3072)
    __shared__ unsigned long long smem_raw[38912 / 8];
    ushort (*pls)[32][76]  = (ushort (*)[32][76])smem_raw;
    float  (*obuf)[32][33] = (float (*)[32][33])smem_raw;
    float  (*lbuf)[32]     = (float (*)[32])((char*)smem_raw + 33792);
    ushort (*oc)[48]       = (ushort (*)[48])((char*)smem_raw + 34816);

    int t  = threadIdx.x;
    int wv = t >> 6;
    int L  = t & 63;
    int nl = L & 15;
    int Q  = L >> 4;
    // XCD-aware bijective swizzle: 512 blocks = 8 XCDs x 64; whole grid is co-resident
    // (2 blocks/CU), so block i lands on XCD (i&7). Remap so each XCD's 64 blocks are
    // consecutive work items = half of one batch -> per-XCD f/ht set 512 KB, L2-resident.
    int bid = blockIdx.x;
    int swz = (bid & 7) * 64 + (bid >> 3);
    int b  = swz >> 7;
    int q0 = (swz & 127) * 32;

    const ushort* fb  = f  + (size_t)b * N_TOK * CR;
    const ushort* htb = ht + (size_t)b * CR * N_TOK;

    bf16x8 gB0 = *(const bf16x8*)(g + ((size_t)b * N_TOK + q0 + nl) * CR + Q * 8);
    bf16x8 gB1 = *(const bf16x8*)(g + ((size_t)b * N_TOK + q0 + 16 + nl) * CR + Q * 8);

    f32x4 acc00 = {0,0,0,0}, acc01 = {0,0,0,0};   // [qh][chhalf]
    f32x4 acc10 = {0,0,0,0}, acc11 = {0,0,0,0};
    const f32x4 zf = {0,0,0,0};
    float lsum0 = 0.f, lsum1 = 0.f;

    // prefetch QK A-frags (f) for iter 0
    int key0 = wv * SEG;
    bf16x8 Ac0 = *(const bf16x8*)(fb + (size_t)(key0 +  0 + nl) * CR + Q * 8);
    bf16x8 Ac1 = *(const bf16x8*)(fb + (size_t)(key0 + 16 + nl) * CR + Q * 8);
    bf16x8 Ac2 = *(const bf16x8*)(fb + (size_t)(key0 + 32 + nl) * CR + Q * 8);
    bf16x8 Ac3 = *(const bf16x8*)(fb + (size_t)(key0 + 48 + nl) * CR + Q * 8);

    #pragma unroll 2
    for (int it = 0; it < NITER; ++it) {
        int kc = wv * SEG + it * KT;
        // issue ht B-frags now (consumed at end of body)
        const ushort* hk = htb + (size_t)nl * N_TOK + kc;
        bf16x8 b00 = *(const bf16x8*)(hk + Q * 8);
        bf16x8 b01 = *(const bf16x8*)(hk + (size_t)16 * N_TOK + Q * 8);
        bf16x8 b10 = *(const bf16x8*)(hk + 32 + Q * 8);
        bf16x8 b11 = *(const bf16x8*)(hk + (size_t)16 * N_TOK + 32 + Q * 8);
        // issue next iteration's A-frags (kept valid on last iter)
        int kn = wv * SEG + ((it + 1 < NITER) ? it + 1 : 0) * KT;
        const ushort* fn = fb + (size_t)kn * CR;
        bf16x8 An0 = *(const bf16x8*)(fn + (size_t)( 0 + nl) * CR + Q * 8);
        bf16x8 An1 = *(const bf16x8*)(fn + (size_t)(16 + nl) * CR + Q * 8);
        bf16x8 An2 = *(const bf16x8*)(fn + (size_t)(32 + nl) * CR + Q * 8);
        bf16x8 An3 = *(const bf16x8*)(fn + (size_t)(48 + nl) * CR + Q * 8);

        // QK^T for both query halves: S^T[key][query]
        f32x4 s00 = __builtin_amdgcn_mfma_f32_16x16x32_bf16(Ac0, gB0, zf, 0, 0, 0);
        f32x4 s01 = __builtin_amdgcn_mfma_f32_16x16x32_bf16(Ac1, gB0, zf, 0, 0, 0);
        f32x4 s02 = __builtin_amdgcn_mfma_f32_16x16x32_bf16(Ac2, gB0, zf, 0, 0, 0);
        f32x4 s03 = __builtin_amdgcn_mfma_f32_16x16x32_bf16(Ac3, gB0, zf, 0, 0, 0);
        f32x4 s10 = __builtin_amdgcn_mfma_f32_16x16x32_bf16(Ac0, gB1, zf, 0, 0, 0);
        f32x4 s11 = __builtin_amdgcn_mfma_f32_16x16x32_bf16(Ac1, gB1, zf, 0, 0, 0);
        f32x4 s12 = __builtin_amdgcn_mfma_f32_16x16x32_bf16(Ac2, gB1, zf, 0, 0, 0);
        f32x4 s13 = __builtin_amdgcn_mfma_f32_16x16x32_bf16(Ac3, gB1, zf, 0, 0, 0);

        // p = exp2(s): one v_exp_f32 each (no shift — cancels in p/sum); pack bf16; LDS transpose
        #pragma unroll
        for (int qh = 0; qh < 2; ++qh) {
            f32x4 v0 = qh ? s10 : s00, v1 = qh ? s11 : s01;
            f32x4 v2 = qh ? s12 : s02, v3 = qh ? s13 : s03;
            int row = qh * 16 + nl;
            float p0 = fast_exp2(v0[0]), p1 = fast_exp2(v0[1]);
            float p2 = fast_exp2(v0[2]), p3 = fast_exp2(v0[3]);
            float s4 = ((p0+p1)+(p2+p3));
            uint2 w; w.x = pk2bf(p0,p1); w.y = pk2bf(p2,p3);
            *(uint2*)&pls[wv][row][ 0 + Q * 4] = w;
            p0 = fast_exp2(v1[0]); p1 = fast_exp2(v1[1]);
            p2 = fast_exp2(v1[2]); p3 = fast_exp2(v1[3]);
            s4 += ((p0+p1)+(p2+p3));
            w.x = pk2bf(p0,p1); w.y = pk2bf(p2,p3);
            *(uint2*)&pls[wv][row][16 + Q * 4] = w;
            p0 = fast_exp2(v2[0]); p1 = fast_exp2(v2[1]);
            p2 = fast_exp2(v2[2]); p3 = fast_exp2(v2[3]);
            s4 += ((p0+p1)+(p2+p3));
            w.x = pk2bf(p0,p1); w.y = pk2bf(p2,p3);
            *(uint2*)&pls[wv][row][32 + Q * 4] = w;
            p0 = fast_exp2(v3[0]); p1 = fast_exp2(v3[1]);
            p2 = fast_exp2(v3[2]); p3 = fast_exp2(v3[3]);
            s4 += ((p0+p1)+(p2+p3));
            w.x = pk2bf(p0,p1); w.y = pk2bf(p2,p3);
            *(uint2*)&pls[wv][row][48 + Q * 4] = w;
            if (qh) lsum1 += s4; else lsum0 += s4;
        }

        // read back as PV A-frags (DS is in-order per wave: RAW safe, compiler emits lgkmcnt)
        bf16x8 aP00 = *(const bf16x8*)&pls[wv][     nl][ 0 + Q * 8];
        bf16x8 aP01 = *(const bf16x8*)&pls[wv][     nl][32 + Q * 8];
        bf16x8 aP10 = *(const bf16x8*)&pls[wv][16 + nl][ 0 + Q * 8];
        bf16x8 aP11 = *(const bf16x8*)&pls[wv][16 + nl][32 + Q * 8];

        acc00 = __builtin_amdgcn_mfma_f32_16x16x32_bf16(aP00, b00, acc00, 0, 0, 0);
        acc01 = __builtin_amdgcn_mfma_f32_16x16x32_bf16(aP00, b01, acc01, 0, 0, 0);
        acc10 = __builtin_amdgcn_mfma_f32_16x16x32_bf16(aP10, b00, acc10, 0, 0, 0);
        acc11 = __builtin_amdgcn_mfma_f32_16x16x32_bf16(aP10, b01, acc11, 0, 0, 0);
        acc00 = __builtin_amdgcn_mfma_f32_16x16x32_bf16(aP01, b10, acc00, 0, 0, 0);
        acc01 = __builtin_amdgcn_mfma_f32_16x16x32_bf16(aP01, b11, acc01, 0, 0, 0);
        acc10 = __builtin_amdgcn_mfma_f32_16x16x32_bf16(aP11, b10, acc10, 0, 0, 0);
        acc11 = __builtin_amdgcn_mfma_f32_16x16x32_bf16(aP11, b11, acc11, 0, 0, 0);

        Ac0 = An0; Ac1 = An1; Ac2 = An2; Ac3 = An3;
    }

    lsum0 += __shfl_xor(lsum0, 16); lsum0 += __shfl_xor(lsum0, 32);
    lsum1 += __shfl_xor(lsum1, 16); lsum1 += __shfl_xor(lsum1, 32);

    __syncthreads();   // all pls reads done before aliasing as obuf
    #pragma unroll
    for (int r = 0; r < 4; ++r) {
        obuf[wv][     Q * 4 + r][nl]      = acc00[r];
        obuf[wv][     Q * 4 + r][16 + nl] = acc01[r];
        obuf[wv][16 + Q * 4 + r][nl]      = acc10[r];
        obuf[wv][16 + Q * 4 + r][16 + nl] = acc11[r];
    }
    if (L < 16) { lbuf[wv][nl] = lsum0; lbuf[wv][16 + nl] = lsum1; }
    __syncthreads();

    {
        int ch = t & 31, qb = t >> 5;   // 512 thr -> 2 (q,ch) each
        #pragma unroll
        for (int qq = qb; qq < 32; qq += 16) {
            float s = 0.f, Lq = 0.f;
            #pragma unroll
            for (int w = 0; w < 8; ++w) { s += obuf[w][qq][ch]; Lq += lbuf[w][qq]; }
            oc[qq][ch] = f2bf(s / Lq);
        }
    }
    __syncthreads();

    // fused epilogue: out = gamma*(o@Wv + bv) + x ; wave wv covers out-ch [wv*32, wv*32+32)
    bf16x8 aO0 = *(const bf16x8*)&oc[     nl][Q * 8];
    bf16x8 aO1 = *(const bf16x8*)&oc[16 + nl][Q * 8];
    float gm = gamma[0];
    const float* xb = x   + ((size_t)b * N_TOK + q0) * CH;
    float*       ob = out + ((size_t)b * N_TOK + q0) * CH;
    #pragma unroll
    for (int i = 0; i < 2; ++i) {
        int nb = wv * 2 + i;
        bf16x8 bW = *(const bf16x8*)(wvt + (size_t)(nb * 16 + nl) * CR + Q * 8);
        f32x4 d0 = __builtin_amdgcn_mfma_f32_16x16x32_bf16(aO0, bW, zf, 0, 0, 0);
        f32x4 d1 = __builtin_amdgcn_mfma_f32_16x16x32_bf16(aO1, bW, zf, 0, 0, 0);
        int c = nb * 16 + nl;
        float bvc = bv[c];
        #pragma unroll
        for (int r = 0; r < 4; ++r) {
            int qa = Q * 4 + r;
            ob[qa * CH + c]        = fmaf(gm, d0[r] + bvc, xb[qa * CH + c]);
            ob[(16 + qa) * CH + c] = fmaf(gm, d1[r] + bvc, xb[(16 + qa) * CH + c]);
        }
    }
}

extern "C" void kernel_launch(void* const* d_in, const int* in_sizes, int n_in,
                              void* d_out, int out_size, void* d_ws, size_t ws_size,
                              hipStream_t stream) {
    const float* x     = (const float*)d_in[0];
    const float* Wf    = (const float*)d_in[1];
    const float* bf_   = (const float*)d_in[2];
    const float* Wg    = (const float*)d_in[3];
    const float* bg    = (const float*)d_in[4];
    const float* Wh    = (const float*)d_in[5];
    const float* bh    = (const float*)d_in[6];
    const float* Wv    = (const float*)d_in[7];
    const float* bv    = (const float*)d_in[8];
    const float* gamma = (const float*)d_in[9];
    float* out = (float*)d_out;

    const size_t T = (size_t)B_SZ * N_TOK * CR;     // 524288
    ushort* fo  = (ushort*)d_ws;
    ushort* go  = fo + T;
    ushort* hto = go + T;
    ushort* wvt = hto + T;                          // 256*32
    ushort* wft = wvt + CH * CR;                    // 32*256 each
    ushort* wgt = wft + CH * CR;
    ushort* wht = wgt + CH * CR;

    prep_kernel<<<4, 256, 0, stream>>>(Wf, Wg, Wh, Wv, wft, wgt, wht, wvt);
    proj_kernel<<<B_SZ * N_TOK / 16, 256, 0, stream>>>(x, wft, wgt, wht, bf_, bg, bh, fo, go, hto);
    attn_kernel<<<B_SZ * (N_TOK / 32), 512, 0, stream>>>(fo, go, hto, wvt, bv, gamma, x, out);
}

// Round 3
// 120.776 us; speedup vs baseline: 1.0860x; 1.0395x over previous
//
#include <hip/hip_runtime.h>

#define B_SZ  4
#define N_TOK 4096   // H*W
#define CH    256
#define CR    32
#define SEG   512    // keys per wave (split-K segment), 8 waves/block
#define KT    64     // keys per iteration
#define NITER (SEG / KT)
#define LOG2E 1.44269504f

typedef __attribute__((ext_vector_type(8))) short bf16x8;  // 8 bf16 = 4 VGPRs
typedef __attribute__((ext_vector_type(4))) float f32x4;

__device__ inline ushort f2bf(float x) {           // RNE fp32->bf16
    uint u = __float_as_uint(x);
    u += 0x7fff + ((u >> 16) & 1);
    return (ushort)(u >> 16);
}
__device__ inline uint pk2bf(float a, float b) {   // [bf16(b)|bf16(a)], truncate
    return __builtin_amdgcn_perm(__float_as_uint(b), __float_as_uint(a), 0x07060302);
}
__device__ inline float fast_exp2(float x) {       // raw v_exp_f32 (1 instr) when available
#if __has_builtin(__builtin_amdgcn_exp2f)
    return __builtin_amdgcn_exp2f(x);
#else
    return exp2f(x);
#endif
}

// ---------- Kernel A: MFMA projections. Self-stages Wf/Wg/Wh (no prep kernel).
// Each block: 256 thr = 4 waves; wave wv owns 16 tokens x full K=256 (no split-K,
// no barrier-idle epilogue). g is scaled by log2(e). ----------
__global__ __launch_bounds__(256) void proj_kernel(
    const float* __restrict__ x,
    const float* __restrict__ Wf, const float* __restrict__ Wg, const float* __restrict__ Wh,
    const float* __restrict__ bf_, const float* __restrict__ bg, const float* __restrict__ bh,
    ushort* __restrict__ fo, ushort* __restrict__ go, ushort* __restrict__ hto)
{
    // W^T staged bf16: [mat][out_ch 32][K 256 + pad 8] -> 50688 B.
    // Row stride 528 B: ds_read_b128 spreads 64 lanes uniformly (8 lanes x 8
    // disjoint 4-bank groups = the 8-phase b128 optimum); stage writes are
    // 128 B-contiguous per wave (lane = K-row).
    __shared__ ushort wst[3][32][264];
    int t = threadIdx.x;

    {   // stage: thread t = K-row t; fully-coalesced float4 reads, contiguous ds writes
        float4 r4[8];
        const float* rf = (const float*)&r4[0];
        #pragma unroll
        for (int q4 = 0; q4 < 8; ++q4) r4[q4] = *(const float4*)(Wf + (size_t)t * CR + q4 * 4);
        #pragma unroll
        for (int j = 0; j < 32; ++j) wst[0][j][t] = f2bf(rf[j]);
        #pragma unroll
        for (int q4 = 0; q4 < 8; ++q4) r4[q4] = *(const float4*)(Wg + (size_t)t * CR + q4 * 4);
        #pragma unroll
        for (int j = 0; j < 32; ++j) wst[1][j][t] = f2bf(rf[j]);
        #pragma unroll
        for (int q4 = 0; q4 < 8; ++q4) r4[q4] = *(const float4*)(Wh + (size_t)t * CR + q4 * 4);
        #pragma unroll
        for (int j = 0; j < 32; ++j) wst[2][j][t] = f2bf(rf[j]);
    }
    __syncthreads();

    int wv = t >> 6, L = t & 63, nl = L & 15, Q = L >> 4;
    int row_t = blockIdx.x * 64 + wv * 16;          // wave-private 16-token tile
    int b = row_t >> 12, tok0 = row_t & 4095;       // 64 | 4096: never straddles batches

    const float* xrow = x + (size_t)(row_t + nl) * CH;
    f32x4 A[6];
    #pragma unroll
    for (int i = 0; i < 6; ++i) A[i] = (f32x4){0.f, 0.f, 0.f, 0.f};

    #pragma unroll
    for (int kk = 0; kk < 8; ++kk) {
        int off = kk * 32 + Q * 8;
        float4 lo = *(const float4*)(xrow + off);
        float4 hi = *(const float4*)(xrow + off + 4);
        bf16x8 xa;
        xa[0] = (short)f2bf(lo.x); xa[1] = (short)f2bf(lo.y);
        xa[2] = (short)f2bf(lo.z); xa[3] = (short)f2bf(lo.w);
        xa[4] = (short)f2bf(hi.x); xa[5] = (short)f2bf(hi.y);
        xa[6] = (short)f2bf(hi.z); xa[7] = (short)f2bf(hi.w);

        bf16x8 wf0 = *(const bf16x8*)&wst[0][nl][off];
        bf16x8 wf1 = *(const bf16x8*)&wst[0][16 + nl][off];
        bf16x8 wg0 = *(const bf16x8*)&wst[1][nl][off];
        bf16x8 wg1 = *(const bf16x8*)&wst[1][16 + nl][off];
        bf16x8 wh0 = *(const bf16x8*)&wst[2][nl][off];
        bf16x8 wh1 = *(const bf16x8*)&wst[2][16 + nl][off];

        A[0] = __builtin_amdgcn_mfma_f32_16x16x32_bf16(xa, wf0, A[0], 0, 0, 0);
        A[1] = __builtin_amdgcn_mfma_f32_16x16x32_bf16(xa, wf1, A[1], 0, 0, 0);
        A[2] = __builtin_amdgcn_mfma_f32_16x16x32_bf16(xa, wg0, A[2], 0, 0, 0);
        A[3] = __builtin_amdgcn_mfma_f32_16x16x32_bf16(xa, wg1, A[3], 0, 0, 0);
        A[4] = __builtin_amdgcn_mfma_f32_16x16x32_bf16(wh0, xa, A[4], 0, 0, 0);  // h^T
        A[5] = __builtin_amdgcn_mfma_f32_16x16x32_bf16(wh1, xa, A[5], 0, 0, 0);
    }

    // epilogue: every wave stores its own 16 tokens
    float bF0 = bf_[nl], bF1 = bf_[16 + nl];
    float bG0 = bg[nl] * LOG2E, bG1 = bg[16 + nl] * LOG2E;
    #pragma unroll
    for (int r = 0; r < 4; ++r) {
        size_t ro = (size_t)(row_t + Q * 4 + r) * CR;
        fo[ro + nl]      = f2bf(A[0][r] + bF0);
        fo[ro + 16 + nl] = f2bf(A[1][r] + bF1);
        go[ro + nl]      = f2bf(fmaf(A[2][r], LOG2E, bG0));
        go[ro + 16 + nl] = f2bf(fmaf(A[3][r], LOG2E, bG1));
    }
    ushort* hb = hto + (size_t)b * CR * N_TOK + tok0 + nl;
    #pragma unroll
    for (int r = 0; r < 4; ++r) {
        int ch = Q * 4 + r;
        hb[(size_t)ch * N_TOK]        = f2bf(A[4][r] + bh[ch]);
        hb[(size_t)(16 + ch) * N_TOK] = f2bf(A[5][r] + bh[16 + ch]);
    }
}

// ---------- Kernel B: attention — 8 waves x 512-key split-K, 32 queries/block, pipelined (R6 structure) ----------
// R9 = R8 main loop unchanged (XCD-bijective swizzle, shift-free exp2) +
//      epilogue reads Wv fp32 directly (prep kernel deleted).
__global__ __launch_bounds__(512, 4) void attn_kernel(
    const ushort* __restrict__ f, const ushort* __restrict__ g,
    const ushort* __restrict__ ht, const float* __restrict__ Wv,
    const float* __restrict__ bv, const float* __restrict__ gamma,
    const float* __restrict__ x, float* __restrict__ out)
{
    // 38912 B shared, aliased: K-loop = pls[8][32][76] ushort;
    // post-barrier = obuf[8][32][33] f32 (33792) + lbuf[8][32] (1024) + oc[32][48] ushort (3072)
    __shared__ unsigned long long smem_raw[38912 / 8];
    ushort (*pls)[32][76]  = (ushort (*)[32][76])smem_raw;
    float  (*obuf)[32][33] = (float (*)[32][33])smem_raw;
    float  (*lbuf)[32]     = (float (*)[32])((char*)smem_raw + 33792);
    ushort (*oc)[48]       = (ushort (*)[48])((char*)smem_raw + 34816);

    int t  = threadIdx.x;
    int wv = t >> 6;
    int L  = t & 63;
    int nl = L & 15;
    int Q  = L >> 4;
    // XCD-aware bijective swizzle: 512 blocks = 8 XCDs x 64; whole grid co-resident
    // (2 blocks/CU). Each XCD's 64 blocks = half of one batch -> f/ht set 512 KB, L2-resident.
    int bid = blockIdx.x;
    int swz = (bid & 7) * 64 + (bid >> 3);
    int b  = swz >> 7;
    int q0 = (swz & 127) * 32;

    const ushort* fb  = f  + (size_t)b * N_TOK * CR;
    const ushort* htb = ht + (size_t)b * CR * N_TOK;

    bf16x8 gB0 = *(const bf16x8*)(g + ((size_t)b * N_TOK + q0 + nl) * CR + Q * 8);
    bf16x8 gB1 = *(const bf16x8*)(g + ((size_t)b * N_TOK + q0 + 16 + nl) * CR + Q * 8);

    f32x4 acc00 = {0,0,0,0}, acc01 = {0,0,0,0};   // [qh][chhalf]
    f32x4 acc10 = {0,0,0,0}, acc11 = {0,0,0,0};
    const f32x4 zf = {0,0,0,0};
    float lsum0 = 0.f, lsum1 = 0.f;

    // prefetch QK A-frags (f) for iter 0
    int key0 = wv * SEG;
    bf16x8 Ac0 = *(const bf16x8*)(fb + (size_t)(key0 +  0 + nl) * CR + Q * 8);
    bf16x8 Ac1 = *(const bf16x8*)(fb + (size_t)(key0 + 16 + nl) * CR + Q * 8);
    bf16x8 Ac2 = *(const bf16x8*)(fb + (size_t)(key0 + 32 + nl) * CR + Q * 8);
    bf16x8 Ac3 = *(const bf16x8*)(fb + (size_t)(key0 + 48 + nl) * CR + Q * 8);

    #pragma unroll 2
    for (int it = 0; it < NITER; ++it) {
        int kc = wv * SEG + it * KT;
        // issue ht B-frags now (consumed at end of body)
        const ushort* hk = htb + (size_t)nl * N_TOK + kc;
        bf16x8 b00 = *(const bf16x8*)(hk + Q * 8);
        bf16x8 b01 = *(const bf16x8*)(hk + (size_t)16 * N_TOK + Q * 8);
        bf16x8 b10 = *(const bf16x8*)(hk + 32 + Q * 8);
        bf16x8 b11 = *(const bf16x8*)(hk + (size_t)16 * N_TOK + 32 + Q * 8);
        // issue next iteration's A-frags (kept valid on last iter)
        int kn = wv * SEG + ((it + 1 < NITER) ? it + 1 : 0) * KT;
        const ushort* fn = fb + (size_t)kn * CR;
        bf16x8 An0 = *(const bf16x8*)(fn + (size_t)( 0 + nl) * CR + Q * 8);
        bf16x8 An1 = *(const bf16x8*)(fn + (size_t)(16 + nl) * CR + Q * 8);
        bf16x8 An2 = *(const bf16x8*)(fn + (size_t)(32 + nl) * CR + Q * 8);
        bf16x8 An3 = *(const bf16x8*)(fn + (size_t)(48 + nl) * CR + Q * 8);

        // QK^T for both query halves: S^T[key][query]
        f32x4 s00 = __builtin_amdgcn_mfma_f32_16x16x32_bf16(Ac0, gB0, zf, 0, 0, 0);
        f32x4 s01 = __builtin_amdgcn_mfma_f32_16x16x32_bf16(Ac1, gB0, zf, 0, 0, 0);
        f32x4 s02 = __builtin_amdgcn_mfma_f32_16x16x32_bf16(Ac2, gB0, zf, 0, 0, 0);
        f32x4 s03 = __builtin_amdgcn_mfma_f32_16x16x32_bf16(Ac3, gB0, zf, 0, 0, 0);
        f32x4 s10 = __builtin_amdgcn_mfma_f32_16x16x32_bf16(Ac0, gB1, zf, 0, 0, 0);
        f32x4 s11 = __builtin_amdgcn_mfma_f32_16x16x32_bf16(Ac1, gB1, zf, 0, 0, 0);
        f32x4 s12 = __builtin_amdgcn_mfma_f32_16x16x32_bf16(Ac2, gB1, zf, 0, 0, 0);
        f32x4 s13 = __builtin_amdgcn_mfma_f32_16x16x32_bf16(Ac3, gB1, zf, 0, 0, 0);

        // p = exp2(s): one v_exp_f32 each (no shift — cancels in p/sum); pack bf16; LDS transpose
        #pragma unroll
        for (int qh = 0; qh < 2; ++qh) {
            f32x4 v0 = qh ? s10 : s00, v1 = qh ? s11 : s01;
            f32x4 v2 = qh ? s12 : s02, v3 = qh ? s13 : s03;
            int row = qh * 16 + nl;
            float p0 = fast_exp2(v0[0]), p1 = fast_exp2(v0[1]);
            float p2 = fast_exp2(v0[2]), p3 = fast_exp2(v0[3]);
            float s4 = ((p0+p1)+(p2+p3));
            uint2 w; w.x = pk2bf(p0,p1); w.y = pk2bf(p2,p3);
            *(uint2*)&pls[wv][row][ 0 + Q * 4] = w;
            p0 = fast_exp2(v1[0]); p1 = fast_exp2(v1[1]);
            p2 = fast_exp2(v1[2]); p3 = fast_exp2(v1[3]);
            s4 += ((p0+p1)+(p2+p3));
            w.x = pk2bf(p0,p1); w.y = pk2bf(p2,p3);
            *(uint2*)&pls[wv][row][16 + Q * 4] = w;
            p0 = fast_exp2(v2[0]); p1 = fast_exp2(v2[1]);
            p2 = fast_exp2(v2[2]); p3 = fast_exp2(v2[3]);
            s4 += ((p0+p1)+(p2+p3));
            w.x = pk2bf(p0,p1); w.y = pk2bf(p2,p3);
            *(uint2*)&pls[wv][row][32 + Q * 4] = w;
            p0 = fast_exp2(v3[0]); p1 = fast_exp2(v3[1]);
            p2 = fast_exp2(v3[2]); p3 = fast_exp2(v3[3]);
            s4 += ((p0+p1)+(p2+p3));
            w.x = pk2bf(p0,p1); w.y = pk2bf(p2,p3);
            *(uint2*)&pls[wv][row][48 + Q * 4] = w;
            if (qh) lsum1 += s4; else lsum0 += s4;
        }

        // read back as PV A-frags (DS is in-order per wave: RAW safe, compiler emits lgkmcnt)
        bf16x8 aP00 = *(const bf16x8*)&pls[wv][     nl][ 0 + Q * 8];
        bf16x8 aP01 = *(const bf16x8*)&pls[wv][     nl][32 + Q * 8];
        bf16x8 aP10 = *(const bf16x8*)&pls[wv][16 + nl][ 0 + Q * 8];
        bf16x8 aP11 = *(const bf16x8*)&pls[wv][16 + nl][32 + Q * 8];

        acc00 = __builtin_amdgcn_mfma_f32_16x16x32_bf16(aP00, b00, acc00, 0, 0, 0);
        acc01 = __builtin_amdgcn_mfma_f32_16x16x32_bf16(aP00, b01, acc01, 0, 0, 0);
        acc10 = __builtin_amdgcn_mfma_f32_16x16x32_bf16(aP10, b00, acc10, 0, 0, 0);
        acc11 = __builtin_amdgcn_mfma_f32_16x16x32_bf16(aP10, b01, acc11, 0, 0, 0);
        acc00 = __builtin_amdgcn_mfma_f32_16x16x32_bf16(aP01, b10, acc00, 0, 0, 0);
        acc01 = __builtin_amdgcn_mfma_f32_16x16x32_bf16(aP01, b11, acc01, 0, 0, 0);
        acc10 = __builtin_amdgcn_mfma_f32_16x16x32_bf16(aP11, b10, acc10, 0, 0, 0);
        acc11 = __builtin_amdgcn_mfma_f32_16x16x32_bf16(aP11, b11, acc11, 0, 0, 0);

        Ac0 = An0; Ac1 = An1; Ac2 = An2; Ac3 = An3;
    }

    lsum0 += __shfl_xor(lsum0, 16); lsum0 += __shfl_xor(lsum0, 32);
    lsum1 += __shfl_xor(lsum1, 16); lsum1 += __shfl_xor(lsum1, 32);

    __syncthreads();   // all pls reads done before aliasing as obuf
    #pragma unroll
    for (int r = 0; r < 4; ++r) {
        obuf[wv][     Q * 4 + r][nl]      = acc00[r];
        obuf[wv][     Q * 4 + r][16 + nl] = acc01[r];
        obuf[wv][16 + Q * 4 + r][nl]      = acc10[r];
        obuf[wv][16 + Q * 4 + r][16 + nl] = acc11[r];
    }
    if (L < 16) { lbuf[wv][nl] = lsum0; lbuf[wv][16 + nl] = lsum1; }
    __syncthreads();

    {
        int ch = t & 31, qb = t >> 5;   // 512 thr -> 2 (q,ch) each
        #pragma unroll
        for (int qq = qb; qq < 32; qq += 16) {
            float s = 0.f, Lq = 0.f;
            #pragma unroll
            for (int w = 0; w < 8; ++w) { s += obuf[w][qq][ch]; Lq += lbuf[w][qq]; }
            oc[qq][ch] = f2bf(s / Lq);
        }
    }
    __syncthreads();

    // fused epilogue: out = gamma*(o@Wv + bv) + x ; wave wv covers out-ch [wv*32, wv*32+32)
    // Wv read directly as fp32 (stride-CH gather, 32 KB total -> L2-hot), cvt inline.
    bf16x8 aO0 = *(const bf16x8*)&oc[     nl][Q * 8];
    bf16x8 aO1 = *(const bf16x8*)&oc[16 + nl][Q * 8];
    float gm = gamma[0];
    const float* xb = x   + ((size_t)b * N_TOK + q0) * CH;
    float*       ob = out + ((size_t)b * N_TOK + q0) * CH;
    #pragma unroll
    for (int i = 0; i < 2; ++i) {
        int nb = wv * 2 + i;
        int c = nb * 16 + nl;
        const float* wvp = Wv + c;          // Wv[k][c], k stride CH
        bf16x8 bW;
        #pragma unroll
        for (int j = 0; j < 8; ++j) bW[j] = (short)f2bf(wvp[(size_t)(Q * 8 + j) * CH]);
        f32x4 d0 = __builtin_amdgcn_mfma_f32_16x16x32_bf16(aO0, bW, zf, 0, 0, 0);
        f32x4 d1 = __builtin_amdgcn_mfma_f32_16x16x32_bf16(aO1, bW, zf, 0, 0, 0);
        float bvc = bv[c];
        #pragma unroll
        for (int r = 0; r < 4; ++r) {
            int qa = Q * 4 + r;
            ob[qa * CH + c]        = fmaf(gm, d0[r] + bvc, xb[qa * CH + c]);
            ob[(16 + qa) * CH + c] = fmaf(gm, d1[r] + bvc, xb[(16 + qa) * CH + c]);
        }
    }
}

extern "C" void kernel_launch(void* const* d_in, const int* in_sizes, int n_in,
                              void* d_out, int out_size, void* d_ws, size_t ws_size,
                              hipStream_t stream) {
    const float* x     = (const float*)d_in[0];
    const float* Wf    = (const float*)d_in[1];
    const float* bf_   = (const float*)d_in[2];
    const float* Wg    = (const float*)d_in[3];
    const float* bg    = (const float*)d_in[4];
    const float* Wh    = (const float*)d_in[5];
    const float* bh    = (const float*)d_in[6];
    const float* Wv    = (const float*)d_in[7];
    const float* bv    = (const float*)d_in[8];
    const float* gamma = (const float*)d_in[9];
    float* out = (float*)d_out;

    const size_t T = (size_t)B_SZ * N_TOK * CR;     // 524288
    ushort* fo  = (ushort*)d_ws;
    ushort* go  = fo + T;
    ushort* hto = go + T;

    proj_kernel<<<B_SZ * N_TOK / 64, 256, 0, stream>>>(x, Wf, Wg, Wh, bf_, bg, bh, fo, go, hto);
    attn_kernel<<<B_SZ * (N_TOK / 32), 512, 0, stream>>>(fo, go, hto, Wv, bv, gamma, x, out);
}

// Round 4
// 112.633 us; speedup vs baseline: 1.1645x; 1.0723x over previous
//
#include <hip/hip_runtime.h>

#define B_SZ  4
#define N_TOK 4096   // H*W
#define CH    256
#define CR    32
#define SEG   256    // keys per wave (split-K segment), 16 waves/block
#define KT    32     // keys per iteration
#define NITER (SEG / KT)
#define LOG2E 1.44269504f

typedef __attribute__((ext_vector_type(8))) short bf16x8;  // 8 bf16 = 4 VGPRs
typedef __attribute__((ext_vector_type(4))) float f32x4;

__device__ inline ushort f2bf(float x) {           // RNE fp32->bf16
    uint u = __float_as_uint(x);
    u += 0x7fff + ((u >> 16) & 1);
    return (ushort)(u >> 16);
}
__device__ inline uint pk2bf(float a, float b) {   // [bf16(b)|bf16(a)], truncate
    return __builtin_amdgcn_perm(__float_as_uint(b), __float_as_uint(a), 0x07060302);
}
__device__ inline float fast_exp2(float x) {       // raw v_exp_f32 (1 instr) when available
#if __has_builtin(__builtin_amdgcn_exp2f)
    return __builtin_amdgcn_exp2f(x);
#else
    return exp2f(x);
#endif
}

// ---------- Kernel A: MFMA projections. Self-stages Wf/Wg/Wh (no prep kernel).
// Each block: 256 thr = 4 waves; wave wv owns 16 tokens x full K=256. g scaled by log2(e). ----------
__global__ __launch_bounds__(256) void proj_kernel(
    const float* __restrict__ x,
    const float* __restrict__ Wf, const float* __restrict__ Wg, const float* __restrict__ Wh,
    const float* __restrict__ bf_, const float* __restrict__ bg, const float* __restrict__ bh,
    ushort* __restrict__ fo, ushort* __restrict__ go, ushort* __restrict__ hto)
{
    __shared__ ushort wst[3][32][264];   // W^T bf16, row stride 528 B
    int t = threadIdx.x;

    {   // stage: thread t = K-row t; coalesced float4 reads, contiguous ds writes
        float4 r4[8];
        const float* rf = (const float*)&r4[0];
        #pragma unroll
        for (int q4 = 0; q4 < 8; ++q4) r4[q4] = *(const float4*)(Wf + (size_t)t * CR + q4 * 4);
        #pragma unroll
        for (int j = 0; j < 32; ++j) wst[0][j][t] = f2bf(rf[j]);
        #pragma unroll
        for (int q4 = 0; q4 < 8; ++q4) r4[q4] = *(const float4*)(Wg + (size_t)t * CR + q4 * 4);
        #pragma unroll
        for (int j = 0; j < 32; ++j) wst[1][j][t] = f2bf(rf[j]);
        #pragma unroll
        for (int q4 = 0; q4 < 8; ++q4) r4[q4] = *(const float4*)(Wh + (size_t)t * CR + q4 * 4);
        #pragma unroll
        for (int j = 0; j < 32; ++j) wst[2][j][t] = f2bf(rf[j]);
    }
    __syncthreads();

    int wv = t >> 6, L = t & 63, nl = L & 15, Q = L >> 4;
    int row_t = blockIdx.x * 64 + wv * 16;
    int b = row_t >> 12, tok0 = row_t & 4095;

    const float* xrow = x + (size_t)(row_t + nl) * CH;
    f32x4 A[6];
    #pragma unroll
    for (int i = 0; i < 6; ++i) A[i] = (f32x4){0.f, 0.f, 0.f, 0.f};

    #pragma unroll
    for (int kk = 0; kk < 8; ++kk) {
        int off = kk * 32 + Q * 8;
        float4 lo = *(const float4*)(xrow + off);
        float4 hi = *(const float4*)(xrow + off + 4);
        bf16x8 xa;
        xa[0] = (short)f2bf(lo.x); xa[1] = (short)f2bf(lo.y);
        xa[2] = (short)f2bf(lo.z); xa[3] = (short)f2bf(lo.w);
        xa[4] = (short)f2bf(hi.x); xa[5] = (short)f2bf(hi.y);
        xa[6] = (short)f2bf(hi.z); xa[7] = (short)f2bf(hi.w);

        bf16x8 wf0 = *(const bf16x8*)&wst[0][nl][off];
        bf16x8 wf1 = *(const bf16x8*)&wst[0][16 + nl][off];
        bf16x8 wg0 = *(const bf16x8*)&wst[1][nl][off];
        bf16x8 wg1 = *(const bf16x8*)&wst[1][16 + nl][off];
        bf16x8 wh0 = *(const bf16x8*)&wst[2][nl][off];
        bf16x8 wh1 = *(const bf16x8*)&wst[2][16 + nl][off];

        A[0] = __builtin_amdgcn_mfma_f32_16x16x32_bf16(xa, wf0, A[0], 0, 0, 0);
        A[1] = __builtin_amdgcn_mfma_f32_16x16x32_bf16(xa, wf1, A[1], 0, 0, 0);
        A[2] = __builtin_amdgcn_mfma_f32_16x16x32_bf16(xa, wg0, A[2], 0, 0, 0);
        A[3] = __builtin_amdgcn_mfma_f32_16x16x32_bf16(xa, wg1, A[3], 0, 0, 0);
        A[4] = __builtin_amdgcn_mfma_f32_16x16x32_bf16(wh0, xa, A[4], 0, 0, 0);  // h^T
        A[5] = __builtin_amdgcn_mfma_f32_16x16x32_bf16(wh1, xa, A[5], 0, 0, 0);
    }

    float bF0 = bf_[nl], bF1 = bf_[16 + nl];
    float bG0 = bg[nl] * LOG2E, bG1 = bg[16 + nl] * LOG2E;
    #pragma unroll
    for (int r = 0; r < 4; ++r) {
        size_t ro = (size_t)(row_t + Q * 4 + r) * CR;
        fo[ro + nl]      = f2bf(A[0][r] + bF0);
        fo[ro + 16 + nl] = f2bf(A[1][r] + bF1);
        go[ro + nl]      = f2bf(fmaf(A[2][r], LOG2E, bG0));
        go[ro + 16 + nl] = f2bf(fmaf(A[3][r], LOG2E, bG1));
    }
    ushort* hb = hto + (size_t)b * CR * N_TOK + tok0 + nl;
    #pragma unroll
    for (int r = 0; r < 4; ++r) {
        int ch = Q * 4 + r;
        hb[(size_t)ch * N_TOK]        = f2bf(A[4][r] + bh[ch]);
        hb[(size_t)(16 + ch) * N_TOK] = f2bf(A[5][r] + bh[16 + ch]);
    }
}

// ---------- Kernel B: attention — R10: 64 queries/block, 16 waves x 256-key split-K, KT=32.
// Halves block count -> halves f/ht re-read traffic; per-iter instruction mix identical to R6
// loop; occupancy unchanged (16 waves/CU = 4/SIMD). XCD-bijective swizzle, shift-free exp2. ----------
__global__ __launch_bounds__(1024, 4) void attn_kernel(
    const ushort* __restrict__ f, const ushort* __restrict__ g,
    const ushort* __restrict__ ht, const float* __restrict__ Wv,
    const float* __restrict__ bv, const float* __restrict__ gamma,
    const float* __restrict__ x, float* __restrict__ out)
{
    // 81920 B shared, aliased:
    //   K-loop:  pls[16][64][40] ushort (row stride 80 B: 16B-aligned b128 reads, <=2-way banks)
    //   post:    obuf[8][64][33] f32 (67584) + lbuf[16][64] f32 (4096 @67584) + oc[64][48] (6144 @71680)
    __shared__ unsigned long long smem_raw[81920 / 8];
    ushort (*pls)[64][40]  = (ushort (*)[64][40])smem_raw;
    float  (*obuf)[64][33] = (float (*)[64][33])smem_raw;
    float  (*lbuf)[64]     = (float (*)[64])((char*)smem_raw + 67584);
    ushort (*oc)[48]       = (ushort (*)[48])((char*)smem_raw + 71680);

    int t  = threadIdx.x;
    int wv = t >> 6;           // 0..15
    int L  = t & 63;
    int nl = L & 15;
    int Q  = L >> 4;
    // XCD swizzle: 256 blocks = 8 XCDs x 32 (bijective); per-XCD f/ht set = 1 batch = 512 KB.
    int bid = blockIdx.x;
    int swz = (bid & 7) * 32 + (bid >> 3);
    int b  = swz >> 6;
    int q0 = (swz & 63) * 64;

    const ushort* fb  = f  + (size_t)b * N_TOK * CR;
    const ushort* htb = ht + (size_t)b * CR * N_TOK;

    bf16x8 gB[4];
    #pragma unroll
    for (int qh = 0; qh < 4; ++qh)
        gB[qh] = *(const bf16x8*)(g + ((size_t)b * N_TOK + q0 + qh * 16 + nl) * CR + Q * 8);

    f32x4 acc[4][2];
    #pragma unroll
    for (int i = 0; i < 4; ++i) { acc[i][0] = (f32x4){0,0,0,0}; acc[i][1] = (f32x4){0,0,0,0}; }
    const f32x4 zf = {0,0,0,0};
    float ls0 = 0.f, ls1 = 0.f, ls2 = 0.f, ls3 = 0.f;

    int key0 = wv * SEG;
    bf16x8 Ac0 = *(const bf16x8*)(fb + (size_t)(key0 +      nl) * CR + Q * 8);
    bf16x8 Ac1 = *(const bf16x8*)(fb + (size_t)(key0 + 16 + nl) * CR + Q * 8);

    #pragma unroll 2
    for (int it = 0; it < NITER; ++it) {
        int kc = key0 + it * KT;
        // ht B-frags (consumed at loop bottom)
        const ushort* hk = htb + (size_t)nl * N_TOK + kc;
        bf16x8 bh0 = *(const bf16x8*)(hk + Q * 8);
        bf16x8 bh1 = *(const bf16x8*)(hk + (size_t)16 * N_TOK + Q * 8);
        // next iteration's f A-frags (kept valid on last iter)
        int kn = key0 + ((it + 1 < NITER) ? it + 1 : 0) * KT;
        bf16x8 An0 = *(const bf16x8*)(fb + (size_t)(kn +      nl) * CR + Q * 8);
        bf16x8 An1 = *(const bf16x8*)(fb + (size_t)(kn + 16 + nl) * CR + Q * 8);

        // QK^T + exp2 + pack + LDS transpose, per 16-query group
        #pragma unroll
        for (int qh = 0; qh < 4; ++qh) {
            f32x4 s0 = __builtin_amdgcn_mfma_f32_16x16x32_bf16(Ac0, gB[qh], zf, 0, 0, 0);
            f32x4 s1 = __builtin_amdgcn_mfma_f32_16x16x32_bf16(Ac1, gB[qh], zf, 0, 0, 0);
            int row = qh * 16 + nl;
            float p0 = fast_exp2(s0[0]), p1 = fast_exp2(s0[1]);
            float p2 = fast_exp2(s0[2]), p3 = fast_exp2(s0[3]);
            float s4 = ((p0 + p1) + (p2 + p3));
            uint2 w; w.x = pk2bf(p0, p1); w.y = pk2bf(p2, p3);
            *(uint2*)&pls[wv][row][ 0 + Q * 4] = w;
            p0 = fast_exp2(s1[0]); p1 = fast_exp2(s1[1]);
            p2 = fast_exp2(s1[2]); p3 = fast_exp2(s1[3]);
            s4 += ((p0 + p1) + (p2 + p3));
            w.x = pk2bf(p0, p1); w.y = pk2bf(p2, p3);
            *(uint2*)&pls[wv][row][16 + Q * 4] = w;
            if (qh == 0) ls0 += s4; else if (qh == 1) ls1 += s4;
            else if (qh == 2) ls2 += s4; else ls3 += s4;
        }

        // read back as PV A-frags (wave-private DS, in-order: RAW safe)
        bf16x8 aP0 = *(const bf16x8*)&pls[wv][     nl][Q * 8];
        bf16x8 aP1 = *(const bf16x8*)&pls[wv][16 + nl][Q * 8];
        bf16x8 aP2 = *(const bf16x8*)&pls[wv][32 + nl][Q * 8];
        bf16x8 aP3 = *(const bf16x8*)&pls[wv][48 + nl][Q * 8];

        acc[0][0] = __builtin_amdgcn_mfma_f32_16x16x32_bf16(aP0, bh0, acc[0][0], 0, 0, 0);
        acc[0][1] = __builtin_amdgcn_mfma_f32_16x16x32_bf16(aP0, bh1, acc[0][1], 0, 0, 0);
        acc[1][0] = __builtin_amdgcn_mfma_f32_16x16x32_bf16(aP1, bh0, acc[1][0], 0, 0, 0);
        acc[1][1] = __builtin_amdgcn_mfma_f32_16x16x32_bf16(aP1, bh1, acc[1][1], 0, 0, 0);
        acc[2][0] = __builtin_amdgcn_mfma_f32_16x16x32_bf16(aP2, bh0, acc[2][0], 0, 0, 0);
        acc[2][1] = __builtin_amdgcn_mfma_f32_16x16x32_bf16(aP2, bh1, acc[2][1], 0, 0, 0);
        acc[3][0] = __builtin_amdgcn_mfma_f32_16x16x32_bf16(aP3, bh0, acc[3][0], 0, 0, 0);
        acc[3][1] = __builtin_amdgcn_mfma_f32_16x16x32_bf16(aP3, bh1, acc[3][1], 0, 0, 0);

        Ac0 = An0; Ac1 = An1;
    }

    // reduce lsum across the 4 Q-quarters (lanes nl, nl+16, nl+32, nl+48)
    ls0 += __shfl_xor(ls0, 16); ls0 += __shfl_xor(ls0, 32);
    ls1 += __shfl_xor(ls1, 16); ls1 += __shfl_xor(ls1, 32);
    ls2 += __shfl_xor(ls2, 16); ls2 += __shfl_xor(ls2, 32);
    ls3 += __shfl_xor(ls3, 16); ls3 += __shfl_xor(ls3, 32);

    __syncthreads();   // all pls reads done before aliasing as obuf

    // two-stage wave reduction: waves 8..15 spill to LDS; waves 0..7 add in-register
    if (wv >= 8) {
        #pragma unroll
        for (int qh = 0; qh < 4; ++qh)
            #pragma unroll
            for (int r = 0; r < 4; ++r) {
                obuf[wv - 8][qh * 16 + Q * 4 + r][nl]      = acc[qh][0][r];
                obuf[wv - 8][qh * 16 + Q * 4 + r][16 + nl] = acc[qh][1][r];
            }
    }
    if (L < 16) {
        lbuf[wv][     nl] = ls0; lbuf[wv][16 + nl] = ls1;
        lbuf[wv][32 + nl] = ls2; lbuf[wv][48 + nl] = ls3;
    }
    __syncthreads();
    if (wv < 8) {
        #pragma unroll
        for (int qh = 0; qh < 4; ++qh)
            #pragma unroll
            for (int r = 0; r < 4; ++r) {
                obuf[wv][qh * 16 + Q * 4 + r][nl]      += acc[qh][0][r];
                obuf[wv][qh * 16 + Q * 4 + r][16 + nl] += acc[qh][1][r];
            }
    }
    __syncthreads();

    {
        int ch = t & 31, qb = t >> 5;   // 1024 thr -> 2 (q,ch) each
        #pragma unroll
        for (int qq = qb; qq < 64; qq += 32) {
            float s = 0.f, Lq = 0.f;
            #pragma unroll
            for (int w = 0; w < 8; ++w) s += obuf[w][qq][ch];
            #pragma unroll
            for (int w = 0; w < 16; ++w) Lq += lbuf[w][qq];
            oc[qq][ch] = f2bf(s / Lq);
        }
    }
    __syncthreads();

    // fused epilogue: out = gamma*(o@Wv + bv) + x ; wave wv covers out-ch [wv*16, wv*16+16)
    float gm = gamma[0];
    const float* xb = x   + ((size_t)b * N_TOK + q0) * CH;
    float*       ob = out + ((size_t)b * N_TOK + q0) * CH;
    int c = wv * 16 + nl;
    const float* wvp = Wv + c;               // Wv[k][c], k stride CH
    bf16x8 bW;
    #pragma unroll
    for (int j = 0; j < 8; ++j) bW[j] = (short)f2bf(wvp[(size_t)(Q * 8 + j) * CH]);
    float bvc = bv[c];
    #pragma unroll
    for (int qg = 0; qg < 4; ++qg) {
        bf16x8 aO = *(const bf16x8*)&oc[qg * 16 + nl][Q * 8];
        f32x4 d = __builtin_amdgcn_mfma_f32_16x16x32_bf16(aO, bW, zf, 0, 0, 0);
        #pragma unroll
        for (int r = 0; r < 4; ++r) {
            int qa = qg * 16 + Q * 4 + r;
            ob[qa * CH + c] = fmaf(gm, d[r] + bvc, xb[qa * CH + c]);
        }
    }
}

extern "C" void kernel_launch(void* const* d_in, const int* in_sizes, int n_in,
                              void* d_out, int out_size, void* d_ws, size_t ws_size,
                              hipStream_t stream) {
    const float* x     = (const float*)d_in[0];
    const float* Wf    = (const float*)d_in[1];
    const float* bf_   = (const float*)d_in[2];
    const float* Wg    = (const float*)d_in[3];
    const float* bg    = (const float*)d_in[4];
    const float* Wh    = (const float*)d_in[5];
    const float* bh    = (const float*)d_in[6];
    const float* Wv    = (const float*)d_in[7];
    const float* bv    = (const float*)d_in[8];
    const float* gamma = (const float*)d_in[9];
    float* out = (float*)d_out;

    const size_t T = (size_t)B_SZ * N_TOK * CR;     // 524288
    ushort* fo  = (ushort*)d_ws;
    ushort* go  = fo + T;
    ushort* hto = go + T;

    proj_kernel<<<B_SZ * N_TOK / 64, 256, 0, stream>>>(x, Wf, Wg, Wh, bf_, bg, bh, fo, go, hto);
    attn_kernel<<<B_SZ * (N_TOK / 64), 1024, 0, stream>>>(fo, go, hto, Wv, bv, gamma, x, out);
}

// Round 5
// 111.490 us; speedup vs baseline: 1.1764x; 1.0103x over previous
//
#include <hip/hip_runtime.h>

#define B_SZ  4
#define N_TOK 4096   // H*W
#define CH    256
#define CR    32
#define SEG   256    // keys per wave (split-K segment), 16 waves/block
#define KT    32     // keys per iteration
#define NITER (SEG / KT)
#define LOG2E 1.44269504f

typedef __attribute__((ext_vector_type(8))) short bf16x8;  // 8 bf16 = 4 VGPRs
typedef __attribute__((ext_vector_type(4))) float f32x4;

__device__ inline ushort f2bf(float x) {           // RNE fp32->bf16
    uint u = __float_as_uint(x);
    u += 0x7fff + ((u >> 16) & 1);
    return (ushort)(u >> 16);
}
__device__ inline uint pk2bf(float a, float b) {   // [bf16(b)|bf16(a)], truncate
    return __builtin_amdgcn_perm(__float_as_uint(b), __float_as_uint(a), 0x07060302);
}
__device__ inline float fast_exp2(float x) {       // raw v_exp_f32 (1 instr) when available
#if __has_builtin(__builtin_amdgcn_exp2f)
    return __builtin_amdgcn_exp2f(x);
#else
    return exp2f(x);
#endif
}

// exp2 both score frags of one 16-query group, pack bf16, write the LDS-transpose row.
// Returns the partial rowsum contribution.
__device__ inline float exp_pack_row(const f32x4 s0, const f32x4 s1, ushort* rp, int Q) {
    float p0 = fast_exp2(s0[0]), p1 = fast_exp2(s0[1]);
    float p2 = fast_exp2(s0[2]), p3 = fast_exp2(s0[3]);
    float s4 = ((p0 + p1) + (p2 + p3));
    uint2 w; w.x = pk2bf(p0, p1); w.y = pk2bf(p2, p3);
    *(uint2*)(rp + Q * 4) = w;
    p0 = fast_exp2(s1[0]); p1 = fast_exp2(s1[1]);
    p2 = fast_exp2(s1[2]); p3 = fast_exp2(s1[3]);
    s4 += ((p0 + p1) + (p2 + p3));
    w.x = pk2bf(p0, p1); w.y = pk2bf(p2, p3);
    *(uint2*)(rp + 16 + Q * 4) = w;
    return s4;
}

// ---------- Kernel A: MFMA projections. Self-stages Wf/Wg/Wh (no prep kernel).
// Each block: 256 thr = 4 waves; wave wv owns 16 tokens x full K=256. g scaled by log2(e). ----------
__global__ __launch_bounds__(256) void proj_kernel(
    const float* __restrict__ x,
    const float* __restrict__ Wf, const float* __restrict__ Wg, const float* __restrict__ Wh,
    const float* __restrict__ bf_, const float* __restrict__ bg, const float* __restrict__ bh,
    ushort* __restrict__ fo, ushort* __restrict__ go, ushort* __restrict__ hto)
{
    __shared__ ushort wst[3][32][264];   // W^T bf16, row stride 528 B
    int t = threadIdx.x;

    {   // stage: thread t = K-row t; coalesced float4 reads, contiguous ds writes
        float4 r4[8];
        const float* rf = (const float*)&r4[0];
        #pragma unroll
        for (int q4 = 0; q4 < 8; ++q4) r4[q4] = *(const float4*)(Wf + (size_t)t * CR + q4 * 4);
        #pragma unroll
        for (int j = 0; j < 32; ++j) wst[0][j][t] = f2bf(rf[j]);
        #pragma unroll
        for (int q4 = 0; q4 < 8; ++q4) r4[q4] = *(const float4*)(Wg + (size_t)t * CR + q4 * 4);
        #pragma unroll
        for (int j = 0; j < 32; ++j) wst[1][j][t] = f2bf(rf[j]);
        #pragma unroll
        for (int q4 = 0; q4 < 8; ++q4) r4[q4] = *(const float4*)(Wh + (size_t)t * CR + q4 * 4);
        #pragma unroll
        for (int j = 0; j < 32; ++j) wst[2][j][t] = f2bf(rf[j]);
    }
    __syncthreads();

    int wv = t >> 6, L = t & 63, nl = L & 15, Q = L >> 4;
    int row_t = blockIdx.x * 64 + wv * 16;
    int b = row_t >> 12, tok0 = row_t & 4095;

    const float* xrow = x + (size_t)(row_t + nl) * CH;
    f32x4 A[6];
    #pragma unroll
    for (int i = 0; i < 6; ++i) A[i] = (f32x4){0.f, 0.f, 0.f, 0.f};

    #pragma unroll
    for (int kk = 0; kk < 8; ++kk) {
        int off = kk * 32 + Q * 8;
        float4 lo = *(const float4*)(xrow + off);
        float4 hi = *(const float4*)(xrow + off + 4);
        bf16x8 xa;
        xa[0] = (short)f2bf(lo.x); xa[1] = (short)f2bf(lo.y);
        xa[2] = (short)f2bf(lo.z); xa[3] = (short)f2bf(lo.w);
        xa[4] = (short)f2bf(hi.x); xa[5] = (short)f2bf(hi.y);
        xa[6] = (short)f2bf(hi.z); xa[7] = (short)f2bf(hi.w);

        bf16x8 wf0 = *(const bf16x8*)&wst[0][nl][off];
        bf16x8 wf1 = *(const bf16x8*)&wst[0][16 + nl][off];
        bf16x8 wg0 = *(const bf16x8*)&wst[1][nl][off];
        bf16x8 wg1 = *(const bf16x8*)&wst[1][16 + nl][off];
        bf16x8 wh0 = *(const bf16x8*)&wst[2][nl][off];
        bf16x8 wh1 = *(const bf16x8*)&wst[2][16 + nl][off];

        A[0] = __builtin_amdgcn_mfma_f32_16x16x32_bf16(xa, wf0, A[0], 0, 0, 0);
        A[1] = __builtin_amdgcn_mfma_f32_16x16x32_bf16(xa, wf1, A[1], 0, 0, 0);
        A[2] = __builtin_amdgcn_mfma_f32_16x16x32_bf16(xa, wg0, A[2], 0, 0, 0);
        A[3] = __builtin_amdgcn_mfma_f32_16x16x32_bf16(xa, wg1, A[3], 0, 0, 0);
        A[4] = __builtin_amdgcn_mfma_f32_16x16x32_bf16(wh0, xa, A[4], 0, 0, 0);  // h^T
        A[5] = __builtin_amdgcn_mfma_f32_16x16x32_bf16(wh1, xa, A[5], 0, 0, 0);
    }

    float bF0 = bf_[nl], bF1 = bf_[16 + nl];
    float bG0 = bg[nl] * LOG2E, bG1 = bg[16 + nl] * LOG2E;
    #pragma unroll
    for (int r = 0; r < 4; ++r) {
        size_t ro = (size_t)(row_t + Q * 4 + r) * CR;
        fo[ro + nl]      = f2bf(A[0][r] + bF0);
        fo[ro + 16 + nl] = f2bf(A[1][r] + bF1);
        go[ro + nl]      = f2bf(fmaf(A[2][r], LOG2E, bG0));
        go[ro + 16 + nl] = f2bf(fmaf(A[3][r], LOG2E, bG1));
    }
    ushort* hb = hto + (size_t)b * CR * N_TOK + tok0 + nl;
    #pragma unroll
    for (int r = 0; r < 4; ++r) {
        int ch = Q * 4 + r;
        hb[(size_t)ch * N_TOK]        = f2bf(A[4][r] + bh[ch]);
        hb[(size_t)(16 + ch) * N_TOK] = f2bf(A[5][r] + bh[16 + ch]);
    }
}

// ---------- Kernel B: attention — R11: R10 geometry (64 q/block, 16 waves x 256-key split-K,
// KT=32, XCD-bijective swizzle) + intra-iteration modulo schedule: aP reads issue 1-2 qh
// groups ahead of their PV use, so DS round-trip latency hides under exp2/pack work. ----------
__global__ __launch_bounds__(1024, 4) void attn_kernel(
    const ushort* __restrict__ f, const ushort* __restrict__ g,
    const ushort* __restrict__ ht, const float* __restrict__ Wv,
    const float* __restrict__ bv, const float* __restrict__ gamma,
    const float* __restrict__ x, float* __restrict__ out)
{
    // 81920 B shared, aliased:
    //   K-loop:  pls[16][64][40] ushort (row stride 80 B: 16B-aligned b128 reads, <=2-way banks)
    //   post:    obuf[8][64][33] f32 (67584) + lbuf[16][64] f32 (4096 @67584) + oc[64][48] (6144 @71680)
    __shared__ unsigned long long smem_raw[81920 / 8];
    ushort (*pls)[64][40]  = (ushort (*)[64][40])smem_raw;
    float  (*obuf)[64][33] = (float (*)[64][33])smem_raw;
    float  (*lbuf)[64]     = (float (*)[64])((char*)smem_raw + 67584);
    ushort (*oc)[48]       = (ushort (*)[48])((char*)smem_raw + 71680);

    int t  = threadIdx.x;
    int wv = t >> 6;           // 0..15
    int L  = t & 63;
    int nl = L & 15;
    int Q  = L >> 4;
    // XCD swizzle: 256 blocks = 8 XCDs x 32 (bijective); per-XCD f/ht set = 1 batch = 512 KB.
    int bid = blockIdx.x;
    int swz = (bid & 7) * 32 + (bid >> 3);
    int b  = swz >> 6;
    int q0 = (swz & 63) * 64;

    const ushort* fb  = f  + (size_t)b * N_TOK * CR;
    const ushort* htb = ht + (size_t)b * CR * N_TOK;

    bf16x8 gB[4];
    #pragma unroll
    for (int qh = 0; qh < 4; ++qh)
        gB[qh] = *(const bf16x8*)(g + ((size_t)b * N_TOK + q0 + qh * 16 + nl) * CR + Q * 8);

    f32x4 acc[4][2];
    #pragma unroll
    for (int i = 0; i < 4; ++i) { acc[i][0] = (f32x4){0,0,0,0}; acc[i][1] = (f32x4){0,0,0,0}; }
    const f32x4 zf = {0,0,0,0};
    float ls0 = 0.f, ls1 = 0.f, ls2 = 0.f, ls3 = 0.f;

    int key0 = wv * SEG;
    bf16x8 Ac0 = *(const bf16x8*)(fb + (size_t)(key0 +      nl) * CR + Q * 8);
    bf16x8 Ac1 = *(const bf16x8*)(fb + (size_t)(key0 + 16 + nl) * CR + Q * 8);

    #pragma unroll 2
    for (int it = 0; it < NITER; ++it) {
        int kc = key0 + it * KT;
        // ht B-frags (consumed mid/late iter; ~2 qh groups of work covers L2 latency)
        const ushort* hk = htb + (size_t)nl * N_TOK + kc;
        bf16x8 bh0 = *(const bf16x8*)(hk + Q * 8);
        bf16x8 bh1 = *(const bf16x8*)(hk + (size_t)16 * N_TOK + Q * 8);
        // next iteration's f A-frags (kept valid on last iter)
        int kn = key0 + ((it + 1 < NITER) ? it + 1 : 0) * KT;
        bf16x8 An0 = *(const bf16x8*)(fb + (size_t)(kn +      nl) * CR + Q * 8);
        bf16x8 An1 = *(const bf16x8*)(fb + (size_t)(kn + 16 + nl) * CR + Q * 8);

        f32x4 t0, t1;
        // qh0 / qh1: QK + exp2 + pack + transpose-write
        t0 = __builtin_amdgcn_mfma_f32_16x16x32_bf16(Ac0, gB[0], zf, 0, 0, 0);
        t1 = __builtin_amdgcn_mfma_f32_16x16x32_bf16(Ac1, gB[0], zf, 0, 0, 0);
        ls0 += exp_pack_row(t0, t1, &pls[wv][nl][0], Q);
        t0 = __builtin_amdgcn_mfma_f32_16x16x32_bf16(Ac0, gB[1], zf, 0, 0, 0);
        t1 = __builtin_amdgcn_mfma_f32_16x16x32_bf16(Ac1, gB[1], zf, 0, 0, 0);
        ls1 += exp_pack_row(t0, t1, &pls[wv][16 + nl][0], Q);
        // issue P-readbacks for qh0/qh1 (rows already written; wave-private DS is in-order)
        bf16x8 aP0 = *(const bf16x8*)&pls[wv][     nl][Q * 8];
        bf16x8 aP1 = *(const bf16x8*)&pls[wv][16 + nl][Q * 8];
        // qh2 covers aP0/aP1 DS latency
        t0 = __builtin_amdgcn_mfma_f32_16x16x32_bf16(Ac0, gB[2], zf, 0, 0, 0);
        t1 = __builtin_amdgcn_mfma_f32_16x16x32_bf16(Ac1, gB[2], zf, 0, 0, 0);
        ls2 += exp_pack_row(t0, t1, &pls[wv][32 + nl][0], Q);
        bf16x8 aP2 = *(const bf16x8*)&pls[wv][32 + nl][Q * 8];
        acc[0][0] = __builtin_amdgcn_mfma_f32_16x16x32_bf16(aP0, bh0, acc[0][0], 0, 0, 0);
        acc[0][1] = __builtin_amdgcn_mfma_f32_16x16x32_bf16(aP0, bh1, acc[0][1], 0, 0, 0);
        acc[1][0] = __builtin_amdgcn_mfma_f32_16x16x32_bf16(aP1, bh0, acc[1][0], 0, 0, 0);
        acc[1][1] = __builtin_amdgcn_mfma_f32_16x16x32_bf16(aP1, bh1, acc[1][1], 0, 0, 0);
        // qh3 covers aP2 DS latency
        t0 = __builtin_amdgcn_mfma_f32_16x16x32_bf16(Ac0, gB[3], zf, 0, 0, 0);
        t1 = __builtin_amdgcn_mfma_f32_16x16x32_bf16(Ac1, gB[3], zf, 0, 0, 0);
        ls3 += exp_pack_row(t0, t1, &pls[wv][48 + nl][0], Q);
        bf16x8 aP3 = *(const bf16x8*)&pls[wv][48 + nl][Q * 8];
        acc[2][0] = __builtin_amdgcn_mfma_f32_16x16x32_bf16(aP2, bh0, acc[2][0], 0, 0, 0);
        acc[2][1] = __builtin_amdgcn_mfma_f32_16x16x32_bf16(aP2, bh1, acc[2][1], 0, 0, 0);
        acc[3][0] = __builtin_amdgcn_mfma_f32_16x16x32_bf16(aP3, bh0, acc[3][0], 0, 0, 0);
        acc[3][1] = __builtin_amdgcn_mfma_f32_16x16x32_bf16(aP3, bh1, acc[3][1], 0, 0, 0);

        Ac0 = An0; Ac1 = An1;
    }

    // reduce lsum across the 4 Q-quarters (lanes nl, nl+16, nl+32, nl+48)
    ls0 += __shfl_xor(ls0, 16); ls0 += __shfl_xor(ls0, 32);
    ls1 += __shfl_xor(ls1, 16); ls1 += __shfl_xor(ls1, 32);
    ls2 += __shfl_xor(ls2, 16); ls2 += __shfl_xor(ls2, 32);
    ls3 += __shfl_xor(ls3, 16); ls3 += __shfl_xor(ls3, 32);

    __syncthreads();   // all pls reads done before aliasing as obuf

    // two-stage wave reduction: waves 8..15 spill to LDS; waves 0..7 add in-register
    if (wv >= 8) {
        #pragma unroll
        for (int qh = 0; qh < 4; ++qh)
            #pragma unroll
            for (int r = 0; r < 4; ++r) {
                obuf[wv - 8][qh * 16 + Q * 4 + r][nl]      = acc[qh][0][r];
                obuf[wv - 8][qh * 16 + Q * 4 + r][16 + nl] = acc[qh][1][r];
            }
    }
    if (L < 16) {
        lbuf[wv][     nl] = ls0; lbuf[wv][16 + nl] = ls1;
        lbuf[wv][32 + nl] = ls2; lbuf[wv][48 + nl] = ls3;
    }
    __syncthreads();
    if (wv < 8) {
        #pragma unroll
        for (int qh = 0; qh < 4; ++qh)
            #pragma unroll
            for (int r = 0; r < 4; ++r) {
                obuf[wv][qh * 16 + Q * 4 + r][nl]      += acc[qh][0][r];
                obuf[wv][qh * 16 + Q * 4 + r][16 + nl] += acc[qh][1][r];
            }
    }
    __syncthreads();

    {
        int ch = t & 31, qb = t >> 5;   // 1024 thr -> 2 (q,ch) each
        #pragma unroll
        for (int qq = qb; qq < 64; qq += 32) {
            float s = 0.f, Lq = 0.f;
            #pragma unroll
            for (int w = 0; w < 8; ++w) s += obuf[w][qq][ch];
            #pragma unroll
            for (int w = 0; w < 16; ++w) Lq += lbuf[w][qq];
            oc[qq][ch] = f2bf(s / Lq);
        }
    }
    __syncthreads();

    // fused epilogue: out = gamma*(o@Wv + bv) + x ; wave wv covers out-ch [wv*16, wv*16+16)
    float gm = gamma[0];
    const float* xb = x   + ((size_t)b * N_TOK + q0) * CH;
    float*       ob = out + ((size_t)b * N_TOK + q0) * CH;
    int c = wv * 16 + nl;
    const float* wvp = Wv + c;               // Wv[k][c], k stride CH
    bf16x8 bW;
    #pragma unroll
    for (int j = 0; j < 8; ++j) bW[j] = (short)f2bf(wvp[(size_t)(Q * 8 + j) * CH]);
    float bvc = bv[c];
    #pragma unroll
    for (int qg = 0; qg < 4; ++qg) {
        bf16x8 aO = *(const bf16x8*)&oc[qg * 16 + nl][Q * 8];
        f32x4 d = __builtin_amdgcn_mfma_f32_16x16x32_bf16(aO, bW, zf, 0, 0, 0);
        #pragma unroll
        for (int r = 0; r < 4; ++r) {
            int qa = qg * 16 + Q * 4 + r;
            ob[qa * CH + c] = fmaf(gm, d[r] + bvc, xb[qa * CH + c]);
        }
    }
}

extern "C" void kernel_launch(void* const* d_in, const int* in_sizes, int n_in,
                              void* d_out, int out_size, void* d_ws, size_t ws_size,
                              hipStream_t stream) {
    const float* x     = (const float*)d_in[0];
    const float* Wf    = (const float*)d_in[1];
    const float* bf_   = (const float*)d_in[2];
    const float* Wg    = (const float*)d_in[3];
    const float* bg    = (const float*)d_in[4];
    const float* Wh    = (const float*)d_in[5];
    const float* bh    = (const float*)d_in[6];
    const float* Wv    = (const float*)d_in[7];
    const float* bv    = (const float*)d_in[8];
    const float* gamma = (const float*)d_in[9];
    float* out = (float*)d_out;

    const size_t T = (size_t)B_SZ * N_TOK * CR;     // 524288
    ushort* fo  = (ushort*)d_ws;
    ushort* go  = fo + T;
    ushort* hto = go + T;

    proj_kernel<<<B_SZ * N_TOK / 64, 256, 0, stream>>>(x, Wf, Wg, Wh, bf_, bg, bh, fo, go, hto);
    attn_kernel<<<B_SZ * (N_TOK / 64), 1024, 0, stream>>>(fo, go, hto, Wv, bv, gamma, x, out);
}